// Round 3
// baseline (144582.227 us; speedup 1.0000x reference)
//
#include <hip/hip_runtime.h>
#include <hip/hip_cooperative_groups.h>
#include <hip/hip_fp16.h>
#include <math.h>

namespace cg = cooperative_groups;

#define NBLK 256
#define NTHR 1024

__device__ __forceinline__ float fast_rcp(float x) {
#if __has_builtin(__builtin_amdgcn_rcpf)
  return __builtin_amdgcn_rcpf(x);
#else
  return 1.f / x;
#endif
}
__device__ __forceinline__ float fast_sigmoid(float x) {
  return fast_rcp(1.f + __expf(-x));
}
__device__ __forceinline__ float fast_tanh(float x) {
  return 1.f - 2.f * fast_rcp(1.f + __expf(2.f * x));
}

struct Params {
  const float *enc, *pre_w1, *pre_w2, *attn_wi, *attn_wh, *attn_bi, *attn_bh;
  const float *q_w, *k_w, *score_w, *score_b, *conv_w, *loc_w, *loc_b;
  const float *out_wi, *out_wh, *out_bi, *out_bh, *dec_w, *dec_b, *gate_w, *gate_b;
  const int *text_lens, *mel_lens;
  __half *hkeys;
  float *hA, *hO, *attw, *attcum, *ctx, *decin, *ebuf, *zpart, *ctxp, *state;
  float *out_mel, *out_gate, *out_attn, *out_mask;
};

union SMem {
  struct { float sA[16][132]; float sB[16][68]; } ge;
  struct { float xT[128][33]; float part[32][32][9]; float gsum[32][9]; } gr;
  struct {
    union { float wS[16][512]; float qpart[8][512]; float red[16][512]; } big;
    float locS[64][33];
    float qS[512];
    float hA_s[512];
    float awS[94]; float acS[94];
    float eS[64];
  } s3;
  struct { float xh[1024]; float red[1024]; float mel[128]; float p1[256]; } s6;
};

union HU { uint4 u; __half2 h[4]; };

// ---------------- GRU stage: 256 blocks x 2 u's x 32 batches, chunked-K ----------------
template <int HN>  // HN=2: wi phase (in), HN=3: wh phase (hn)
__device__ __forceinline__ void gru_chunk_compute(SMem& sm, const float* wb, float acc[8],
                                                  int cks, int cb) {
#pragma unroll
  for (int j = 0; j < 4; j++) {
    float x = sm.gr.xT[cks * 4 + j][cb];
    const float* wr = wb + (size_t)j * 1536;
    float2 w0 = *(const float2*)(wr);
    float2 w1 = *(const float2*)(wr + 512);
    float2 w2 = *(const float2*)(wr + 1024);
    acc[0] = fmaf(x, w0.x, acc[0]); acc[4] = fmaf(x, w0.y, acc[4]);
    acc[1] = fmaf(x, w1.x, acc[1]); acc[5] = fmaf(x, w1.y, acc[5]);
    acc[HN] = fmaf(x, w2.x, acc[HN]); acc[HN + 4] = fmaf(x, w2.y, acc[HN + 4]);
  }
}

__device__ __forceinline__ void gru_stage(SMem& sm,
    const float* __restrict__ xa, int Da, const float* __restrict__ xb, int Db,
    const float* __restrict__ wi, const float* __restrict__ wh,
    const float* __restrict__ bi, const float* __restrict__ bh,
    const float* __restrict__ hprev, float* __restrict__ hnext,
    int blk, int tid) {
  const int u0 = blk * 2;
  const int nA = Da >> 7, nX = (Da + Db) >> 7, nTot = nX + 4;
  float acc[8] = {0.f, 0.f, 0.f, 0.f, 0.f, 0.f, 0.f, 0.f};
  const int sb = tid >> 5, skq = (tid & 31) * 4;
  const int cb = tid & 31, cks = tid >> 5;
  for (int c = 0; c < nTot; c++) {
    const float* src; int D;
    if (c < nA)      { src = xa + (c << 7); D = Da; }
    else if (c < nX) { src = xb + ((c - nA) << 7); D = Db; }
    else             { src = hprev + ((c - nX) << 7); D = 512; }
    float4 v = *(const float4*)(src + (size_t)sb * D + skq);
    sm.gr.xT[skq + 0][sb] = v.x; sm.gr.xT[skq + 1][sb] = v.y;
    sm.gr.xT[skq + 2][sb] = v.z; sm.gr.xT[skq + 3][sb] = v.w;
    __syncthreads();
    if (c < nX) {
      const float* wb = wi + (size_t)((c << 7) + cks * 4) * 1536 + u0;
      gru_chunk_compute<2>(sm, wb, acc, cks, cb);
    } else {
      const float* wb = wh + (size_t)(((c - nX) << 7) + cks * 4) * 1536 + u0;
      gru_chunk_compute<3>(sm, wb, acc, cks, cb);
    }
    __syncthreads();
  }
  float* pp = &sm.gr.part[cks][cb][0];
#pragma unroll
  for (int c = 0; c < 8; c++) pp[c] = acc[c];
  __syncthreads();
  if (tid < 256) {
    int bb = tid >> 3, c = tid & 7;
    float s = 0.f;
#pragma unroll 8
    for (int ks = 0; ks < 32; ks++) s += sm.gr.part[ks][bb][c];
    sm.gr.gsum[bb][c] = s;
  }
  __syncthreads();
  if (tid < 64) {
    int bb = tid >> 1, ul = tid & 1, u = u0 + ul;
    const float* g = &sm.gr.gsum[bb][ul * 4];
    float r = fast_sigmoid(g[0] + bi[u] + bh[u]);
    float z = fast_sigmoid(g[1] + bi[512 + u] + bh[512 + u]);
    float n = fast_tanh(g[2] + bi[1024 + u] + r * (g[3] + bh[1024 + u]));
    hnext[bb * 512 + u] = (1.f - z) * n + z * hprev[bb * 512 + u];
  }
  __syncthreads();
}

__global__ __launch_bounds__(NTHR) void mega(Params p) {
  cg::grid_group grid = cg::this_grid();
  __shared__ SMem sm;
  const int blk = blockIdx.x, tid = threadIdx.x;

  // ---- phase 0: zero state, mel_mask, keys GEMM (fp16 out) ----
  for (int i = blk * NTHR + tid; i < 122880; i += NBLK * NTHR) p.state[i] = 0.f;
  for (int i = blk * NTHR + tid; i < 12800; i += NBLK * NTHR) {
    int b = i / 400, t = i - b * 400;
    p.out_mask[i] = (t > p.mel_lens[b]) ? 1.f : 0.f;
  }
  for (int rep = 0; rep < 4; rep++) {
    int tile = blk + rep * NBLK;
    int row0 = (tile >> 3) << 7, col0 = (tile & 7) << 6;
    float acc[4][4] = {};
    int r = tid >> 2, kq = tid & 3;
    int tx = tid & 15, ty = tid >> 4;
    for (int k0 = 0; k0 < 1024; k0 += 16) {
      __syncthreads();
      if (tid < 512) {
        float4 a4 = *(const float4*)(p.enc + (size_t)(row0 + r) * 1024 + k0 + kq * 4);
        sm.ge.sA[kq * 4 + 0][r] = a4.x; sm.ge.sA[kq * 4 + 1][r] = a4.y;
        sm.ge.sA[kq * 4 + 2][r] = a4.z; sm.ge.sA[kq * 4 + 3][r] = a4.w;
      }
      if (tid < 256) {
        int kb = tid >> 4, nb = (tid & 15) * 4;
        float4 b4 = *(const float4*)(p.k_w + (size_t)(k0 + kb) * 512 + col0 + nb);
        sm.ge.sB[kb][nb + 0] = b4.x; sm.ge.sB[kb][nb + 1] = b4.y;
        sm.ge.sB[kb][nb + 2] = b4.z; sm.ge.sB[kb][nb + 3] = b4.w;
      }
      __syncthreads();
      if (tid < 512) {
#pragma unroll
        for (int k = 0; k < 16; k++) {
          float ar[4], br[4];
#pragma unroll
          for (int i = 0; i < 4; i++) { ar[i] = sm.ge.sA[k][ty * 4 + i]; br[i] = sm.ge.sB[k][tx * 4 + i]; }
#pragma unroll
          for (int i = 0; i < 4; i++)
#pragma unroll
            for (int j = 0; j < 4; j++) acc[i][j] = fmaf(ar[i], br[j], acc[i][j]);
        }
      }
    }
    if (tid < 512) {
#pragma unroll
      for (int i = 0; i < 4; i++)
#pragma unroll
        for (int j = 0; j < 4; j++)
          p.hkeys[(size_t)(row0 + ty * 4 + i) * 512 + col0 + tx * 4 + j] = __float2half(acc[i][j]);
    }
    __syncthreads();
  }
  grid.sync();

#pragma clang loop unroll(disable)
  for (int step = 0; step < 400; step++) {
    const int par = step & 1;
    float* hA_prev = p.hA + par * 16384;
    float* hA_next = p.hA + (par ^ 1) * 16384;
    float* hO_prev = p.hO + par * 16384;
    float* hO_next = p.hO + (par ^ 1) * 16384;

    // ---- S1: GRU1 ----
    gru_stage(sm, p.decin, 256, p.ctx, 512, p.attn_wi, p.attn_wh, p.attn_bi, p.attn_bh,
              hA_prev, hA_next, blk, tid);
    grid.sync();

    // ---- S3: q(fused) + conv + loc-proj + tanh + score + e + ctx-partials ----
    {
      const int b = blk >> 3, t8 = blk & 7, t0 = t8 << 6;
      const int tlen = p.text_lens[b];
      // stage windows + hA
      for (int j = tid; j < 94; j += NTHR) {
        int pp = t0 - 15 + j;
        bool ok = (unsigned)pp < 512u;
        sm.s3.awS[j] = ok ? p.attw[b * 512 + pp] : 0.f;
        sm.s3.acS[j] = ok ? p.attcum[b * 512 + pp] : 0.f;
      }
      if (tid < 512) sm.s3.hA_s[tid] = hA_next[b * 512 + tid];
      __syncthreads();
      // conv -> locS
      for (int i = tid; i < 2048; i += NTHR) {
        int tt = i >> 5, f = i & 31;
        const float* w0 = p.conv_w + f * 62;
        float a = 0.f;
#pragma unroll
        for (int k = 0; k < 31; k++)
          a = fmaf(w0[k], sm.s3.awS[tt + k], fmaf(w0[31 + k], sm.s3.acS[tt + k], a));
        sm.s3.locS[tt][f] = a;
      }
      // q partials (redundant per t8-block)
      {
        int a4 = tid & 127, ks = tid >> 7;
        float q0 = 0.f, q1 = 0.f, q2 = 0.f, q3 = 0.f;
        const float* qw = p.q_w + a4 * 4;
#pragma unroll 8
        for (int k = ks * 64; k < ks * 64 + 64; k++) {
          float x = sm.s3.hA_s[k];
          float4 w = *(const float4*)(qw + (size_t)k * 512);
          q0 = fmaf(x, w.x, q0); q1 = fmaf(x, w.y, q1);
          q2 = fmaf(x, w.z, q2); q3 = fmaf(x, w.w, q3);
        }
        float* qp = &sm.s3.big.qpart[ks][a4 * 4];
        qp[0] = q0; qp[1] = q1; qp[2] = q2; qp[3] = q3;
      }
      __syncthreads();
      if (tid < 512) {
        float s = p.loc_b[tid];
#pragma unroll
        for (int j = 0; j < 8; j++) s += sm.s3.big.qpart[j][tid];
        sm.s3.qS[tid] = s;
      }
      __syncthreads();
      // acc init: q + keys (fp16)
      const int lane = tid & 63, wv = tid >> 6;
      float acc[4][8];
      float4 qA = *(const float4*)&sm.s3.qS[lane * 8];
      float4 qB = *(const float4*)&sm.s3.qS[lane * 8 + 4];
#pragma unroll
      for (int tt = 0; tt < 4; tt++) {
        int t = t0 + wv * 4 + tt;
        HU raw;
        raw.u = *(const uint4*)(p.hkeys + ((size_t)(b * 512 + t) << 9) + lane * 8);
        float2 k0 = __half22float2(raw.h[0]), k1 = __half22float2(raw.h[1]);
        float2 k2 = __half22float2(raw.h[2]), k3 = __half22float2(raw.h[3]);
        acc[tt][0] = qA.x + k0.x; acc[tt][1] = qA.y + k0.y;
        acc[tt][2] = qA.z + k1.x; acc[tt][3] = qA.w + k1.y;
        acc[tt][4] = qB.x + k2.x; acc[tt][5] = qB.y + k2.y;
        acc[tt][6] = qB.z + k3.x; acc[tt][7] = qB.w + k3.y;
      }
      // loc-proj: acc += locS @ loc_w
      for (int ph = 0; ph < 2; ph++) {
        __syncthreads();
        {
          float4* dst = (float4*)&sm.s3.big.wS[0][0];
          const float4* srcw = (const float4*)(p.loc_w + ph * 8192);
          dst[tid] = srcw[tid];
          dst[tid + 1024] = srcw[tid + 1024];
        }
        __syncthreads();
#pragma unroll
        for (int f2 = 0; f2 < 16; f2++) {
          float4 wA = *(const float4*)&sm.s3.big.wS[f2][lane * 8];
          float4 wB = *(const float4*)&sm.s3.big.wS[f2][lane * 8 + 4];
#pragma unroll
          for (int tt = 0; tt < 4; tt++) {
            float lf = sm.s3.locS[wv * 4 + tt][ph * 16 + f2];
            acc[tt][0] = fmaf(lf, wA.x, acc[tt][0]); acc[tt][1] = fmaf(lf, wA.y, acc[tt][1]);
            acc[tt][2] = fmaf(lf, wA.z, acc[tt][2]); acc[tt][3] = fmaf(lf, wA.w, acc[tt][3]);
            acc[tt][4] = fmaf(lf, wB.x, acc[tt][4]); acc[tt][5] = fmaf(lf, wB.y, acc[tt][5]);
            acc[tt][6] = fmaf(lf, wB.z, acc[tt][6]); acc[tt][7] = fmaf(lf, wB.w, acc[tt][7]);
          }
        }
      }
      // score + e
      float4 sA = *(const float4*)(p.score_w + lane * 8);
      float4 sB = *(const float4*)(p.score_w + lane * 8 + 4);
      float sb = p.score_b[0];
      float e_reg[4];
#pragma unroll
      for (int tt = 0; tt < 4; tt++) {
        float pv = fast_tanh(acc[tt][0]) * sA.x + fast_tanh(acc[tt][1]) * sA.y +
                   fast_tanh(acc[tt][2]) * sA.z + fast_tanh(acc[tt][3]) * sA.w +
                   fast_tanh(acc[tt][4]) * sB.x + fast_tanh(acc[tt][5]) * sB.y +
                   fast_tanh(acc[tt][6]) * sB.z + fast_tanh(acc[tt][7]) * sB.w;
#pragma unroll
        for (int off = 32; off > 0; off >>= 1) pv += __shfl_xor(pv, off, 64);
        int t = t0 + wv * 4 + tt;
        e_reg[tt] = (t > tlen) ? 0.f : __expf(pv + sb);
      }
      if (lane == 0) {
#pragma unroll
        for (int tt = 0; tt < 4; tt++) sm.s3.eS[wv * 4 + tt] = e_reg[tt];
      }
      // ctx partials: cp[a] = sum_t e_t * keys[t][a]
      float cp[8] = {0.f, 0.f, 0.f, 0.f, 0.f, 0.f, 0.f, 0.f};
#pragma unroll
      for (int tt = 0; tt < 4; tt++) {
        int t = t0 + wv * 4 + tt;
        HU raw;
        raw.u = *(const uint4*)(p.hkeys + ((size_t)(b * 512 + t) << 9) + lane * 8);
        float2 k0 = __half22float2(raw.h[0]), k1 = __half22float2(raw.h[1]);
        float2 k2 = __half22float2(raw.h[2]), k3 = __half22float2(raw.h[3]);
        float e = e_reg[tt];
        cp[0] = fmaf(e, k0.x, cp[0]); cp[1] = fmaf(e, k0.y, cp[1]);
        cp[2] = fmaf(e, k1.x, cp[2]); cp[3] = fmaf(e, k1.y, cp[3]);
        cp[4] = fmaf(e, k2.x, cp[4]); cp[5] = fmaf(e, k2.y, cp[5]);
        cp[6] = fmaf(e, k3.x, cp[6]); cp[7] = fmaf(e, k3.y, cp[7]);
      }
      __syncthreads();  // wS reads done; reuse as red
      {
        float4* r0 = (float4*)&sm.s3.big.red[wv][lane * 8];
        r0[0] = make_float4(cp[0], cp[1], cp[2], cp[3]);
        r0[1] = make_float4(cp[4], cp[5], cp[6], cp[7]);
      }
      __syncthreads();
      if (tid < 512) {
        float s = 0.f;
#pragma unroll
        for (int j = 0; j < 16; j++) s += sm.s3.big.red[j][tid];
        p.ctxp[(size_t)(b * 8 + t8) * 512 + tid] = s;
      }
      if (tid < 64) {
        float e = sm.s3.eS[tid];
        p.ebuf[b * 512 + t0 + tid] = e;
        float z = e;
#pragma unroll
        for (int off = 32; off > 0; off >>= 1) z += __shfl_xor(z, off, 64);
        if (tid == 0) p.zpart[b * 8 + t8] = z;
      }
    }
    grid.sync();

    // ---- S4: normalize -> ctx, attw, attcum, out_attn ----
    {
      const int b = blk >> 3, ch = blk & 7;
      if (tid < 128) {
        float Z = 0.f;
#pragma unroll
        for (int j = 0; j < 8; j++) Z += p.zpart[b * 8 + j];
        float invZ = fast_rcp(Z);
        if (tid < 64) {
          int a = ch * 64 + tid;
          float s = 0.f;
#pragma unroll
          for (int j = 0; j < 8; j++) s += p.ctxp[(size_t)(b * 8 + j) * 512 + a];
          p.ctx[b * 512 + a] = s * invZ;
        } else {
          int t = ch * 64 + (tid - 64);
          float v = p.ebuf[b * 512 + t] * invZ;
          p.attw[b * 512 + t] = v;
          p.attcum[b * 512 + t] += v;
          p.out_attn[(size_t)b * 204800 + (size_t)step * 512 + t] = v;
        }
      }
    }
    grid.sync();

    // ---- S5: GRU2 ----
    gru_stage(sm, hA_next, 512, p.ctx, 512, p.out_wi, p.out_wh, p.out_bi, p.out_bh,
              hO_prev, hO_next, blk, tid);
    grid.sync();

    // ---- S6: mel/gate heads + prenet ----
    if (blk < 32) {
      const int b = blk;
      sm.s6.xh[tid] = (tid < 512) ? hO_next[b * 512 + tid] : p.ctx[b * 512 + tid - 512];
      __syncthreads();
      bool masked = step > p.mel_lens[b];
      {
        int m = tid & 127, ks = tid >> 7;
        float a = 0.f;
        const float* dw = p.dec_w + (size_t)(ks * 128) * 128 + m;
#pragma unroll 8
        for (int k = 0; k < 128; k++) { a = fmaf(sm.s6.xh[ks * 128 + k], dw[0], a); dw += 128; }
        sm.s6.red[tid] = a;
      }
      __syncthreads();
      if (tid < 128) {
        float mv = p.dec_b[tid];
#pragma unroll
        for (int j = 0; j < 8; j++) mv += sm.s6.red[tid + j * 128];
        sm.s6.mel[tid] = mv;
        p.out_mel[(size_t)b * 51200 + (size_t)step * 128 + tid] = masked ? 0.f : mv;
      }
      __syncthreads();
      sm.s6.red[tid] = sm.s6.xh[tid] * p.gate_w[tid];
      __syncthreads();
      if (tid < 64) {
        float g = 0.f;
#pragma unroll
        for (int j = 0; j < 16; j++) g += sm.s6.red[tid + j * 64];
#pragma unroll
        for (int off = 32; off > 0; off >>= 1) g += __shfl_xor(g, off, 64);
        if (tid == 0)
          p.out_gate[b * 400 + step] = masked ? 1000.f : (g + p.gate_b[0]);
      }
      __syncthreads();
      {
        int col = tid & 255, ks = tid >> 8;
        float a = 0.f;
        const float* w1 = p.pre_w1 + (size_t)(ks * 32) * 256 + col;
#pragma unroll 8
        for (int k = 0; k < 32; k++) { a = fmaf(sm.s6.mel[ks * 32 + k], w1[0], a); w1 += 256; }
        sm.s6.red[tid] = a;
      }
      __syncthreads();
      if (tid < 256) {
        float a = sm.s6.red[tid] + sm.s6.red[tid + 256] + sm.s6.red[tid + 512] + sm.s6.red[tid + 768];
        sm.s6.p1[tid] = fmaxf(a, 0.f);
      }
      __syncthreads();
      {
        int col = tid & 255, ks = tid >> 8;
        float a = 0.f;
        const float* w2 = p.pre_w2 + (size_t)(ks * 64) * 256 + col;
#pragma unroll 8
        for (int k = 0; k < 64; k++) { a = fmaf(sm.s6.p1[ks * 64 + k], w2[0], a); w2 += 256; }
        sm.s6.red[tid] = a;
      }
      __syncthreads();
      if (tid < 256) {
        float a = sm.s6.red[tid] + sm.s6.red[tid + 256] + sm.s6.red[tid + 512] + sm.s6.red[tid + 768];
        p.decin[b * 256 + tid] = fmaxf(a, 0.f);
      }
    }
    grid.sync();
  }
}

extern "C" void kernel_launch(void* const* d_in, const int* in_sizes, int n_in,
                              void* d_out, int out_size, void* d_ws, size_t ws_size,
                              hipStream_t stream) {
  Params p;
  p.enc       = (const float*)d_in[0];
  p.text_lens = (const int*)d_in[2];
  p.mel_lens  = (const int*)d_in[3];
  p.pre_w1    = (const float*)d_in[5];
  p.pre_w2    = (const float*)d_in[6];
  p.attn_wi   = (const float*)d_in[7];
  p.attn_wh   = (const float*)d_in[8];
  p.attn_bi   = (const float*)d_in[9];
  p.attn_bh   = (const float*)d_in[10];
  p.q_w       = (const float*)d_in[11];
  p.k_w       = (const float*)d_in[12];
  p.score_w   = (const float*)d_in[13];
  p.score_b   = (const float*)d_in[14];
  p.conv_w    = (const float*)d_in[15];
  p.loc_w     = (const float*)d_in[16];
  p.loc_b     = (const float*)d_in[17];
  p.out_wi    = (const float*)d_in[18];
  p.out_wh    = (const float*)d_in[19];
  p.out_bi    = (const float*)d_in[20];
  p.out_bh    = (const float*)d_in[21];
  p.dec_w     = (const float*)d_in[22];
  p.dec_b     = (const float*)d_in[23];
  p.gate_w    = (const float*)d_in[24];
  p.gate_b    = (const float*)d_in[25];

  float* ws = (float*)d_ws;
  p.hkeys  = (__half*)d_ws;            // 16384*512 halfs = 4,194,304 floats worth
  p.hA     = ws + 4194304;             // 2 x 16384
  p.hO     = ws + 4227072;             // 2 x 16384
  p.attw   = ws + 4259840;             // 16384
  p.attcum = ws + 4276224;             // 16384
  p.ctx    = ws + 4292608;             // 16384
  p.decin  = ws + 4308992;             // 8192
  p.ebuf   = ws + 4317184;             // 16384
  p.zpart  = ws + 4333568;             // 256
  p.ctxp   = ws + 4333824;             // 32*8*512 = 131072
  p.state  = p.hA;  // contiguous zero region: hA,hO,attw,attcum,ctx,decin = 122880 floats

  float* out = (float*)d_out;
  p.out_mel  = out;
  p.out_gate = out + 1638400;
  p.out_attn = out + 1651200;
  p.out_mask = out + 8204800;

  void* args[] = { (void*)&p };
  hipLaunchCooperativeKernel((const void*)mega, dim3(NBLK), dim3(NTHR), args, 0, stream);
}

// Round 4
// 103389.734 us; speedup vs baseline: 1.3984x; 1.3984x over previous
//
#include <hip/hip_runtime.h>
#include <hip/hip_cooperative_groups.h>
#include <hip/hip_fp16.h>
#include <math.h>

namespace cg = cooperative_groups;

#define NBLK 256
#define NTHR 1024

__device__ __forceinline__ float fast_rcp(float x) {
#if __has_builtin(__builtin_amdgcn_rcpf)
  return __builtin_amdgcn_rcpf(x);
#else
  return 1.f / x;
#endif
}
__device__ __forceinline__ float fast_sigmoid(float x) { return fast_rcp(1.f + __expf(-x)); }
__device__ __forceinline__ float fast_tanh(float x) { return 1.f - 2.f * fast_rcp(1.f + __expf(2.f * x)); }

union HU2 { unsigned int u; __half2 h; };
union HU4 { uint4 u; __half2 h[4]; };
__device__ __forceinline__ float2 cvt2(unsigned int u) { HU2 t; t.u = u; return __half22float2(t.h); }

struct Params {
  const float *enc, *pre_w1, *pre_w2, *attn_wi, *attn_wh, *attn_bi, *attn_bh;
  const float *q_w, *k_w, *score_w, *score_b, *conv_w, *loc_w, *loc_b;
  const float *out_wi, *out_wh, *out_bi, *out_bh, *dec_w, *dec_b, *gate_w, *gate_b;
  const int *text_lens, *mel_lens;
  __half *hkeys, *gw1, *gw2, *qwT, *locw, *decT, *gateh, *pre1T, *pre2T;
  float *hA, *hO, *attw, *attcum, *ctx, *decin, *ebuf, *zpart, *ctxp, *stateZ;
  float *out_mel, *out_gate, *out_attn, *out_mask;
};

// ---------------- prep: keys GEMM (fp16 out) ----------------
__global__ __launch_bounds__(512) void k_keys(Params p) {
  __shared__ float sA[16][132];
  __shared__ float sB[16][68];
  int tid = threadIdx.x;
  int row0 = blockIdx.x * 128, col0 = blockIdx.y * 64;
  float acc[4][4] = {};
  int r = tid >> 2, kq = tid & 3;
  int tx = tid & 15, ty = tid >> 4;
  for (int k0 = 0; k0 < 1024; k0 += 16) {
    __syncthreads();
    float4 a4 = *(const float4*)(p.enc + (size_t)(row0 + r) * 1024 + k0 + kq * 4);
    sA[kq * 4 + 0][r] = a4.x; sA[kq * 4 + 1][r] = a4.y;
    sA[kq * 4 + 2][r] = a4.z; sA[kq * 4 + 3][r] = a4.w;
    if (tid < 256) {
      int kb = tid >> 4, nb = (tid & 15) * 4;
      float4 b4 = *(const float4*)(p.k_w + (size_t)(k0 + kb) * 512 + col0 + nb);
      sB[kb][nb + 0] = b4.x; sB[kb][nb + 1] = b4.y;
      sB[kb][nb + 2] = b4.z; sB[kb][nb + 3] = b4.w;
    }
    __syncthreads();
#pragma unroll
    for (int k = 0; k < 16; k++) {
      float ar[4], br[4];
#pragma unroll
      for (int i = 0; i < 4; i++) { ar[i] = sA[k][ty * 4 + i]; br[i] = sB[k][tx * 4 + i]; }
#pragma unroll
      for (int i = 0; i < 4; i++)
#pragma unroll
        for (int j = 0; j < 4; j++) acc[i][j] = fmaf(ar[i], br[j], acc[i][j]);
    }
  }
#pragma unroll
  for (int i = 0; i < 4; i++)
#pragma unroll
    for (int j = 0; j < 4; j++)
      p.hkeys[(size_t)(row0 + ty * 4 + i) * 512 + col0 + tx * 4 + j] = __float2half(acc[i][j]);
}

// ---------------- prep: repack weights to fp16 tiles + zero state + mask ----------------
__global__ __launch_bounds__(256) void k_repack(Params p) {
  const int gsz = gridDim.x * 256;
  const int t0 = blockIdx.x * 256 + threadIdx.x;
  // GRU1 tiles: [block(u>>1)][r:1280][ul][4]
  for (int i = t0; i < 512 * 1280; i += gsz) {
    int r = i >> 9, u = i & 511;
    const float* src = (r < 768) ? p.attn_wi + (size_t)r * 1536 : p.attn_wh + (size_t)(r - 768) * 1536;
    __half* d = p.gw1 + ((((size_t)(u >> 1) * 1280 + r) * 2 + (u & 1)) << 2);
    d[0] = __float2half(src[u]); d[1] = __float2half(src[512 + u]);
    d[2] = __float2half(src[1024 + u]); d[3] = __float2half(0.f);
  }
  // GRU2 tiles: [block][r:1536][ul][4]
  for (int i = t0; i < 512 * 1536; i += gsz) {
    int r = i >> 9, u = i & 511;
    const float* src = (r < 1024) ? p.out_wi + (size_t)r * 1536 : p.out_wh + (size_t)(r - 1024) * 1536;
    __half* d = p.gw2 + ((((size_t)(u >> 1) * 1536 + r) * 2 + (u & 1)) << 2);
    d[0] = __float2half(src[u]); d[1] = __float2half(src[512 + u]);
    d[2] = __float2half(src[1024 + u]); d[3] = __float2half(0.f);
  }
  // q_wT[a][k]
  for (int i = t0; i < 512 * 512; i += gsz) {
    int k = i >> 9, a = i & 511;
    p.qwT[(size_t)a * 512 + k] = __float2half(p.q_w[(size_t)k * 512 + a]);
  }
  // loc_w [32][512] direct
  for (int i = t0; i < 16384; i += gsz) p.locw[i] = __float2half(p.loc_w[i]);
  // decT[m][k]
  for (int i = t0; i < 1024 * 128; i += gsz) {
    int k = i >> 7, m = i & 127;
    p.decT[(size_t)m * 1024 + k] = __float2half(p.dec_w[(size_t)k * 128 + m]);
  }
  for (int i = t0; i < 1024; i += gsz) p.gateh[i] = __float2half(p.gate_w[i]);
  // pre1T[pc][m]
  for (int i = t0; i < 128 * 256; i += gsz) {
    int m = i >> 8, pc = i & 255;
    p.pre1T[(size_t)pc * 128 + m] = __float2half(p.pre_w1[(size_t)m * 256 + pc]);
  }
  // pre2T[pc][k]
  for (int i = t0; i < 256 * 256; i += gsz) {
    int k = i >> 8, pc = i & 255;
    p.pre2T[(size_t)pc * 256 + k] = __float2half(p.pre_w2[(size_t)k * 256 + pc]);
  }
  for (int i = t0; i < 122880; i += gsz) p.stateZ[i] = 0.f;
  for (int i = t0; i < 12800; i += gsz) {
    int b = i / 400, t = i - b * 400;
    p.out_mask[i] = (t > p.mel_lens[b]) ? 1.f : 0.f;
  }
}

struct SMemMega {
  uint2 w2[3072];  // persisted GRU2 tile: [r:1536][ul:2] of 4 halfs
  union {
    struct { float xT[64][33]; float part[16][32][2][6]; float gsum[32][2][6]; } gr;
    struct { float locS[64][33]; float aw[94]; float ac[94]; float hA_s[512]; float qS[512];
             float cpred[8][512]; float eS[64]; } s3;
    struct { float xh[1024]; float red[1024]; float mel[128]; float p1[256]; } s6;
  } u;
};

// ---------------- GRU stage: block owns units {2blk, 2blk+1}, full K ----------------
template <bool LDSW>
__device__ __forceinline__ void gru_stage(SMemMega& sm, const uint2* gw, int rows,
    const float* __restrict__ xa, int Da, const float* __restrict__ xb,
    const float* __restrict__ hp, const float* __restrict__ bi, const float* __restrict__ bh,
    float* __restrict__ hnext, int blk, int tid) {
  const int b = tid & 31, ul = (tid >> 5) & 1, ln = tid >> 6;
  const int roff = ln * 4;
  float ai0 = 0.f, ai1 = 0.f, ai2 = 0.f, ah0 = 0.f, ah1 = 0.f, ah2 = 0.f;
  const int nch = rows >> 6, cwi = (rows - 512) >> 6;
  for (int c = 0; c < nch; c++) {
    __syncthreads();
    const int grb = c << 6;
    for (int i = tid; i < 2048; i += NTHR) {
      int b2 = i >> 6, r = i & 63, gr = grb + r;
      float v;
      if (gr < Da) v = xa[b2 * Da + gr];
      else if (gr < Da + 512) v = xb[(b2 << 9) + gr - Da];
      else v = hp[(b2 << 9) + gr - Da - 512];
      sm.u.gr.xT[r][b2] = v;
    }
    __syncthreads();
    if (c < cwi) {
#pragma unroll
      for (int j = 0; j < 4; j++) {
        int gr = grb + roff + j;
        uint2 wv = LDSW ? sm.w2[gr * 2 + ul] : gw[(size_t)gr * 2 + ul];
        float2 f0 = cvt2(wv.x); float2 f1 = cvt2(wv.y);
        float x = sm.u.gr.xT[roff + j][b];
        ai0 = fmaf(x, f0.x, ai0); ai1 = fmaf(x, f0.y, ai1); ai2 = fmaf(x, f1.x, ai2);
      }
    } else {
#pragma unroll
      for (int j = 0; j < 4; j++) {
        int gr = grb + roff + j;
        uint2 wv = LDSW ? sm.w2[gr * 2 + ul] : gw[(size_t)gr * 2 + ul];
        float2 f0 = cvt2(wv.x); float2 f1 = cvt2(wv.y);
        float x = sm.u.gr.xT[roff + j][b];
        ah0 = fmaf(x, f0.x, ah0); ah1 = fmaf(x, f0.y, ah1); ah2 = fmaf(x, f1.x, ah2);
      }
    }
  }
  float* pp = &sm.u.gr.part[ln][b][ul][0];
  pp[0] = ai0; pp[1] = ai1; pp[2] = ai2; pp[3] = ah0; pp[4] = ah1; pp[5] = ah2;
  __syncthreads();
  if (tid < 384) {
    int bb = tid / 12, rem = tid % 12, uu = rem / 6, g = rem % 6;
    float s = 0.f;
#pragma unroll
    for (int l = 0; l < 16; l++) s += sm.u.gr.part[l][bb][uu][g];
    sm.u.gr.gsum[bb][uu][g] = s;
  }
  __syncthreads();
  if (tid < 64) {
    int bb = tid >> 1, uu = tid & 1, ug = blk * 2 + uu;
    const float* g = &sm.u.gr.gsum[bb][uu][0];
    float r = fast_sigmoid(g[0] + g[3] + bi[ug] + bh[ug]);
    float z = fast_sigmoid(g[1] + g[4] + bi[512 + ug] + bh[512 + ug]);
    float n = fast_tanh(g[2] + bi[1024 + ug] + r * (g[5] + bh[1024 + ug]));
    hnext[(bb << 9) + ug] = (1.f - z) * n + z * hp[(bb << 9) + ug];
  }
}

__global__ __launch_bounds__(NTHR, 4) void mega(Params p) {
  cg::grid_group grid = cg::this_grid();
  __shared__ SMemMega sm;
  const int blk = blockIdx.x, tid = threadIdx.x;

  // persist GRU2 tile into LDS (survives all 400 steps)
  {
    const uint2* g2 = (const uint2*)p.gw2 + (size_t)blk * 3072;
    for (int i = tid; i < 3072; i += NTHR) sm.w2[i] = g2[i];
  }
  const uint2* g1 = (const uint2*)p.gw1 + (size_t)blk * 2560;
  grid.sync();  // prep kernels already done (stream order); sync aligns all blocks

#pragma clang loop unroll(disable)
  for (int step = 0; step < 400; step++) {
    const int par = step & 1;
    float* hA_prev = p.hA + par * 16384;
    float* hA_next = p.hA + (par ^ 1) * 16384;
    float* hO_prev = p.hO + par * 16384;
    float* hO_next = p.hO + (par ^ 1) * 16384;

    // ---- S1: GRU1 (streamed private tile) ----
    gru_stage<false>(sm, g1, 1280, p.decin, 256, p.ctx, hA_prev,
                     p.attn_bi, p.attn_bh, hA_next, blk, tid);
    grid.sync();

    // ---- S3: q + conv + loc-proj + tanh + score + e + ctx-partials ----
    {
      const int b = blk >> 3, t8 = blk & 7, t0g = t8 << 6;
      const int tlen = p.text_lens[b];
      for (int j = tid; j < 94; j += NTHR) {
        int pp = t0g - 15 + j;
        bool ok = (unsigned)pp < 512u;
        sm.u.s3.aw[j] = ok ? p.attw[(b << 9) + pp] : 0.f;
        sm.u.s3.ac[j] = ok ? p.attcum[(b << 9) + pp] : 0.f;
      }
      if (tid < 512) sm.u.s3.hA_s[tid] = hA_next[(b << 9) + tid];
      __syncthreads();
      // conv -> locS
      for (int i = tid; i < 2048; i += NTHR) {
        int tt = i >> 5, f = i & 31;
        const float* w0 = p.conv_w + f * 62;
        float a = 0.f;
#pragma unroll
        for (int k = 0; k < 31; k++)
          a = fmaf(w0[k], sm.u.s3.aw[tt + k], fmaf(w0[31 + k], sm.u.s3.ac[tt + k], a));
        sm.u.s3.locS[tt][f] = a;
      }
      // q partials (redundant per block): threads (a, kslice of 2)
      {
        int a = tid & 511, ks = tid >> 9;
        const HU4* qp = (const HU4*)(p.qwT + (size_t)a * 512 + ks * 256);
        float q0 = 0.f, q1 = 0.f;
#pragma unroll 4
        for (int it = 0; it < 32; it++) {
          HU4 raw = qp[it];
          int kb = ks * 256 + it * 8;
#pragma unroll
          for (int h2 = 0; h2 < 4; h2++) {
            float2 w = __half22float2(raw.h[h2]);
            q0 = fmaf(sm.u.s3.hA_s[kb + h2 * 2], w.x, q0);
            q1 = fmaf(sm.u.s3.hA_s[kb + h2 * 2 + 1], w.y, q1);
          }
        }
        sm.u.s3.cpred[ks][a] = q0 + q1;
      }
      __syncthreads();
      if (tid < 512) sm.u.s3.qS[tid] = sm.u.s3.cpred[0][tid] + sm.u.s3.cpred[1][tid] + p.loc_b[tid];
      __syncthreads();
      // scores: 16 waves x 4 t
      const int lane = tid & 63, wv = tid >> 6;
      float acc[4][8];
      float4 qA = *(const float4*)&sm.u.s3.qS[lane * 8];
      float4 qB = *(const float4*)&sm.u.s3.qS[lane * 8 + 4];
#pragma unroll
      for (int j = 0; j < 4; j++) {
        int t = t0g + wv * 4 + j;
        HU4 raw; raw.u = *(const uint4*)(p.hkeys + (((size_t)(b << 9) + t) << 9) + lane * 8);
        float2 k0 = __half22float2(raw.h[0]), k1 = __half22float2(raw.h[1]);
        float2 k2 = __half22float2(raw.h[2]), k3 = __half22float2(raw.h[3]);
        acc[j][0] = qA.x + k0.x; acc[j][1] = qA.y + k0.y;
        acc[j][2] = qA.z + k1.x; acc[j][3] = qA.w + k1.y;
        acc[j][4] = qB.x + k2.x; acc[j][5] = qB.y + k2.y;
        acc[j][6] = qB.z + k3.x; acc[j][7] = qB.w + k3.y;
      }
#pragma unroll 4
      for (int f = 0; f < 32; f++) {
        HU4 rw; rw.u = *(const uint4*)(p.locw + (size_t)f * 512 + lane * 8);
        float2 w0 = __half22float2(rw.h[0]), w1 = __half22float2(rw.h[1]);
        float2 w2 = __half22float2(rw.h[2]), w3 = __half22float2(rw.h[3]);
#pragma unroll
        for (int j = 0; j < 4; j++) {
          float lf = sm.u.s3.locS[wv * 4 + j][f];
          acc[j][0] = fmaf(lf, w0.x, acc[j][0]); acc[j][1] = fmaf(lf, w0.y, acc[j][1]);
          acc[j][2] = fmaf(lf, w1.x, acc[j][2]); acc[j][3] = fmaf(lf, w1.y, acc[j][3]);
          acc[j][4] = fmaf(lf, w2.x, acc[j][4]); acc[j][5] = fmaf(lf, w2.y, acc[j][5]);
          acc[j][6] = fmaf(lf, w3.x, acc[j][6]); acc[j][7] = fmaf(lf, w3.y, acc[j][7]);
        }
      }
      float4 sA = *(const float4*)(p.score_w + lane * 8);
      float4 sB = *(const float4*)(p.score_w + lane * 8 + 4);
      float sbias = p.score_b[0];
      float e_reg[4];
#pragma unroll
      for (int j = 0; j < 4; j++) {
        float pv = fast_tanh(acc[j][0]) * sA.x + fast_tanh(acc[j][1]) * sA.y +
                   fast_tanh(acc[j][2]) * sA.z + fast_tanh(acc[j][3]) * sA.w +
                   fast_tanh(acc[j][4]) * sB.x + fast_tanh(acc[j][5]) * sB.y +
                   fast_tanh(acc[j][6]) * sB.z + fast_tanh(acc[j][7]) * sB.w;
#pragma unroll
        for (int off = 32; off > 0; off >>= 1) pv += __shfl_xor(pv, off, 64);
        int t = t0g + wv * 4 + j;
        e_reg[j] = (t > tlen) ? 0.f : __expf(pv + sbias);
      }
      if (lane == 0) {
#pragma unroll
        for (int j = 0; j < 4; j++) sm.u.s3.eS[wv * 4 + j] = e_reg[j];
      }
      // ctx partials (keys re-read: L2-hot)
      float cp[8] = {0.f, 0.f, 0.f, 0.f, 0.f, 0.f, 0.f, 0.f};
#pragma unroll
      for (int j = 0; j < 4; j++) {
        int t = t0g + wv * 4 + j;
        HU4 raw; raw.u = *(const uint4*)(p.hkeys + (((size_t)(b << 9) + t) << 9) + lane * 8);
        float2 k0 = __half22float2(raw.h[0]), k1 = __half22float2(raw.h[1]);
        float2 k2 = __half22float2(raw.h[2]), k3 = __half22float2(raw.h[3]);
        float e = e_reg[j];
        cp[0] = fmaf(e, k0.x, cp[0]); cp[1] = fmaf(e, k0.y, cp[1]);
        cp[2] = fmaf(e, k1.x, cp[2]); cp[3] = fmaf(e, k1.y, cp[3]);
        cp[4] = fmaf(e, k2.x, cp[4]); cp[5] = fmaf(e, k2.y, cp[5]);
        cp[6] = fmaf(e, k3.x, cp[6]); cp[7] = fmaf(e, k3.y, cp[7]);
      }
      __syncthreads();  // cpred q-scratch reads done
      if (wv < 8) {
        float4* r0 = (float4*)&sm.u.s3.cpred[wv][lane * 8];
        r0[0] = make_float4(cp[0], cp[1], cp[2], cp[3]);
        r0[1] = make_float4(cp[4], cp[5], cp[6], cp[7]);
      }
      __syncthreads();
      if (wv >= 8) {
        float* r0 = &sm.u.s3.cpred[wv - 8][lane * 8];
#pragma unroll
        for (int i = 0; i < 8; i++) r0[i] += cp[i];
      }
      __syncthreads();
      if (tid < 512) {
        float s = 0.f;
#pragma unroll
        for (int j = 0; j < 8; j++) s += sm.u.s3.cpred[j][tid];
        p.ctxp[(size_t)((b << 3) + t8) * 512 + tid] = s;
      }
      if (tid < 64) {
        float e = sm.u.s3.eS[tid];
        p.ebuf[(b << 9) + t0g + tid] = e;
        float z = e;
#pragma unroll
        for (int off = 32; off > 0; off >>= 1) z += __shfl_xor(z, off, 64);
        if (tid == 0) p.zpart[b * 8 + t8] = z;
      }
    }
    grid.sync();

    // ---- S4: normalize -> ctx, attw, attcum, out_attn ----
    {
      const int b = blk >> 3, ch = blk & 7;
      if (tid < 128) {
        float Z = 0.f;
#pragma unroll
        for (int j = 0; j < 8; j++) Z += p.zpart[b * 8 + j];
        float invZ = fast_rcp(Z);
        if (tid < 64) {
          int a = (ch << 6) + tid;
          float s = 0.f;
#pragma unroll
          for (int j = 0; j < 8; j++) s += p.ctxp[(size_t)((b << 3) + j) * 512 + a];
          p.ctx[(b << 9) + a] = s * invZ;
        } else {
          int t = (ch << 6) + (tid - 64);
          float v = p.ebuf[(b << 9) + t] * invZ;
          p.attw[(b << 9) + t] = v;
          p.attcum[(b << 9) + t] += v;
          p.out_attn[(size_t)b * 204800 + (size_t)step * 512 + t] = v;
        }
      }
    }
    grid.sync();

    // ---- S5: GRU2 (LDS-persisted tile) ----
    gru_stage<true>(sm, nullptr, 1536, hA_next, 512, p.ctx, hO_prev,
                    p.out_bi, p.out_bh, hO_next, blk, tid);
    grid.sync();

    // ---- S6: mel/gate + prenet (32 b-blocks) ----
    if (blk < 32) {
      const int b = blk;
      sm.u.s6.xh[tid] = (tid < 512) ? hO_next[(b << 9) + tid] : p.ctx[(b << 9) + tid - 512];
      __syncthreads();
      bool masked = step > p.mel_lens[b];
      {
        int m = tid & 127, ks = tid >> 7;
        const HU4* dp = (const HU4*)(p.decT + (size_t)m * 1024 + ks * 128);
        float a = 0.f;
#pragma unroll 4
        for (int it = 0; it < 16; it++) {
          HU4 raw = dp[it];
          int kb = ks * 128 + it * 8;
#pragma unroll
          for (int h2 = 0; h2 < 4; h2++) {
            float2 w = __half22float2(raw.h[h2]);
            a = fmaf(sm.u.s6.xh[kb + h2 * 2], w.x, a);
            a = fmaf(sm.u.s6.xh[kb + h2 * 2 + 1], w.y, a);
          }
        }
        sm.u.s6.red[tid] = a;
      }
      __syncthreads();
      if (tid < 128) {
        float mv = p.dec_b[tid];
#pragma unroll
        for (int j = 0; j < 8; j++) mv += sm.u.s6.red[tid + j * 128];
        sm.u.s6.mel[tid] = mv;
        p.out_mel[(size_t)b * 51200 + (size_t)step * 128 + tid] = masked ? 0.f : mv;
      }
      __syncthreads();
      sm.u.s6.red[tid] = sm.u.s6.xh[tid] * __half2float(p.gateh[tid]);
      __syncthreads();
      if (tid < 64) {
        float g = 0.f;
#pragma unroll
        for (int j = 0; j < 16; j++) g += sm.u.s6.red[tid + j * 64];
#pragma unroll
        for (int off = 32; off > 0; off >>= 1) g += __shfl_xor(g, off, 64);
        if (tid == 0) p.out_gate[b * 400 + step] = masked ? 1000.f : (g + p.gate_b[0]);
      }
      __syncthreads();
      {
        int pc = tid & 255, ks = tid >> 8;
        const HU4* wp = (const HU4*)(p.pre1T + (size_t)pc * 128 + ks * 32);
        float a = 0.f;
#pragma unroll
        for (int it = 0; it < 4; it++) {
          HU4 raw = wp[it];
          int kb = ks * 32 + it * 8;
#pragma unroll
          for (int h2 = 0; h2 < 4; h2++) {
            float2 w = __half22float2(raw.h[h2]);
            a = fmaf(sm.u.s6.mel[kb + h2 * 2], w.x, a);
            a = fmaf(sm.u.s6.mel[kb + h2 * 2 + 1], w.y, a);
          }
        }
        sm.u.s6.red[tid] = a;
      }
      __syncthreads();
      if (tid < 256) {
        float a = sm.u.s6.red[tid] + sm.u.s6.red[tid + 256] + sm.u.s6.red[tid + 512] + sm.u.s6.red[tid + 768];
        sm.u.s6.p1[tid] = fmaxf(a, 0.f);
      }
      __syncthreads();
      {
        int pc = tid & 255, ks = tid >> 8;
        const HU4* wp = (const HU4*)(p.pre2T + (size_t)pc * 256 + ks * 64);
        float a = 0.f;
#pragma unroll
        for (int it = 0; it < 8; it++) {
          HU4 raw = wp[it];
          int kb = ks * 64 + it * 8;
#pragma unroll
          for (int h2 = 0; h2 < 4; h2++) {
            float2 w = __half22float2(raw.h[h2]);
            a = fmaf(sm.u.s6.p1[kb + h2 * 2], w.x, a);
            a = fmaf(sm.u.s6.p1[kb + h2 * 2 + 1], w.y, a);
          }
        }
        sm.u.s6.red[tid] = a;
      }
      __syncthreads();
      if (tid < 256) {
        float a = sm.u.s6.red[tid] + sm.u.s6.red[tid + 256] + sm.u.s6.red[tid + 512] + sm.u.s6.red[tid + 768];
        p.decin[(b << 8) + tid] = fmaxf(a, 0.f);
      }
    }
    grid.sync();
  }
}

extern "C" void kernel_launch(void* const* d_in, const int* in_sizes, int n_in,
                              void* d_out, int out_size, void* d_ws, size_t ws_size,
                              hipStream_t stream) {
  Params p;
  p.enc       = (const float*)d_in[0];
  p.text_lens = (const int*)d_in[2];
  p.mel_lens  = (const int*)d_in[3];
  p.pre_w1    = (const float*)d_in[5];
  p.pre_w2    = (const float*)d_in[6];
  p.attn_wi   = (const float*)d_in[7];
  p.attn_wh   = (const float*)d_in[8];
  p.attn_bi   = (const float*)d_in[9];
  p.attn_bh   = (const float*)d_in[10];
  p.q_w       = (const float*)d_in[11];
  p.k_w       = (const float*)d_in[12];
  p.score_w   = (const float*)d_in[13];
  p.score_b   = (const float*)d_in[14];
  p.conv_w    = (const float*)d_in[15];
  p.loc_w     = (const float*)d_in[16];
  p.loc_b     = (const float*)d_in[17];
  p.out_wi    = (const float*)d_in[18];
  p.out_wh    = (const float*)d_in[19];
  p.out_bi    = (const float*)d_in[20];
  p.out_bh    = (const float*)d_in[21];
  p.dec_w     = (const float*)d_in[22];
  p.dec_b     = (const float*)d_in[23];
  p.gate_w    = (const float*)d_in[24];
  p.gate_b    = (const float*)d_in[25];

  float* ws = (float*)d_ws;
  p.hkeys  = (__half*)(ws);                    // 8,388,608 halfs
  p.gw1    = (__half*)(ws + 4194304);          // 2,621,440 halfs
  p.gw2    = (__half*)(ws + 5505024);          // 3,145,728 halfs
  p.qwT    = (__half*)(ws + 7077888);          // 262,144
  p.locw   = (__half*)(ws + 7208960);          // 16,384
  p.decT   = (__half*)(ws + 7217152);          // 131,072
  p.gateh  = (__half*)(ws + 7282688);          // 1,024
  p.pre1T  = (__half*)(ws + 7283200);          // 32,768
  p.pre2T  = (__half*)(ws + 7299584);          // 65,536
  p.hA     = ws + 7332352;                     // 2 x 16384
  p.hO     = ws + 7365120;                     // 2 x 16384
  p.attw   = ws + 7397888;                     // 16384
  p.attcum = ws + 7414272;                     // 16384
  p.ctx    = ws + 7430656;                     // 16384
  p.decin  = ws + 7447040;                     // 8192
  p.stateZ = p.hA;                             // contiguous zero region 122,880 floats
  p.ebuf   = ws + 7455232;                     // 16384
  p.zpart  = ws + 7471616;                     // 512
  p.ctxp   = ws + 7472128;                     // 131,072
  float* out = (float*)d_out;
  p.out_mel  = out;
  p.out_gate = out + 1638400;
  p.out_attn = out + 1651200;
  p.out_mask = out + 8204800;

  k_repack<<<2048, 256, 0, stream>>>(p);
  k_keys<<<dim3(128, 8), 512, 0, stream>>>(p);
  void* args[] = { (void*)&p };
  hipLaunchCooperativeKernel((const void*)mega, dim3(NBLK), dim3(NTHR), args, 0, stream);
}

// Round 5
// 68741.583 us; speedup vs baseline: 2.1033x; 1.5040x over previous
//
#include <hip/hip_runtime.h>
#include <hip/hip_fp16.h>
#include <math.h>

#define NBLK 256
#define NTHR 1024

__device__ __forceinline__ float fast_rcp(float x) {
#if __has_builtin(__builtin_amdgcn_rcpf)
  return __builtin_amdgcn_rcpf(x);
#else
  return 1.f / x;
#endif
}
__device__ __forceinline__ float fast_sigmoid(float x) { return fast_rcp(1.f + __expf(-x)); }
__device__ __forceinline__ float fast_tanh(float x) { return 1.f - 2.f * fast_rcp(1.f + __expf(2.f * x)); }

union HU2 { unsigned int u; __half2 h; };
union HU4 { uint4 u; __half2 h[4]; };
__device__ __forceinline__ float2 cvt2(unsigned int u) { HU2 t; t.u = u; return __half22float2(t.h); }

// agent-scope (cache-bypassing) communication primitives
__device__ __forceinline__ void sta(float* p, float v) {
  __hip_atomic_store(p, v, __ATOMIC_RELAXED, __HIP_MEMORY_SCOPE_AGENT);
}
__device__ __forceinline__ float lda(const float* p) {
  return __hip_atomic_load(p, __ATOMIC_RELAXED, __HIP_MEMORY_SCOPE_AGENT);
}

struct Params {
  const float *enc, *pre_w1, *pre_w2, *attn_wi, *attn_wh, *attn_bi, *attn_bh;
  const float *q_w, *k_w, *score_w, *score_b, *conv_w, *loc_w, *loc_b;
  const float *out_wi, *out_wh, *out_bi, *out_bh, *dec_w, *dec_b, *gate_w, *gate_b;
  const int *text_lens, *mel_lens;
  __half *hkeys, *gw1T, *gw2T, *decT, *pre1T, *pre2T, *gateh, *locwh;
  float *hA, *hO, *attw, *attcum, *ctx, *decin, *ebuf, *zpart, *ctxp, *stateZ;
  unsigned *barc, *barg;
  float *out_mel, *out_gate, *out_attn, *out_mask;
};

// lightweight grid barrier: monotone counter, no L2 writeback/invalidate
__device__ __forceinline__ void gbar(unsigned* cnt, unsigned* gen, unsigned* epoch) {
  __syncthreads();  // per-wave s_waitcnt vmcnt(0) before s_barrier drains all stores
  if (threadIdx.x == 0) {
    unsigned e = ++(*epoch);
    asm volatile("s_waitcnt vmcnt(0) lgkmcnt(0)" ::: "memory");
    unsigned arr = __hip_atomic_fetch_add(cnt, 1u, __ATOMIC_RELAXED, __HIP_MEMORY_SCOPE_AGENT);
    if (arr == e * NBLK - 1) {
      __hip_atomic_store(gen, e, __ATOMIC_RELAXED, __HIP_MEMORY_SCOPE_AGENT);
    } else {
      while (__hip_atomic_load(gen, __ATOMIC_RELAXED, __HIP_MEMORY_SCOPE_AGENT) < e)
        __builtin_amdgcn_s_sleep(2);
    }
    asm volatile("" ::: "memory");
  }
  __syncthreads();
}

// ---------------- prep: keys GEMM (fp16 out) ----------------
__global__ __launch_bounds__(512) void k_keys(Params p) {
  __shared__ float sA[16][132];
  __shared__ float sB[16][68];
  int tid = threadIdx.x;
  int row0 = blockIdx.x * 128, col0 = blockIdx.y * 64;
  float acc[4][4] = {};
  int r = tid >> 2, kq = tid & 3;
  int tx = tid & 15, ty = tid >> 4;
  for (int k0 = 0; k0 < 1024; k0 += 16) {
    __syncthreads();
    float4 a4 = *(const float4*)(p.enc + (size_t)(row0 + r) * 1024 + k0 + kq * 4);
    sA[kq * 4 + 0][r] = a4.x; sA[kq * 4 + 1][r] = a4.y;
    sA[kq * 4 + 2][r] = a4.z; sA[kq * 4 + 3][r] = a4.w;
    if (tid < 256) {
      int kb = tid >> 4, nb = (tid & 15) * 4;
      float4 b4 = *(const float4*)(p.k_w + (size_t)(k0 + kb) * 512 + col0 + nb);
      sB[kb][nb + 0] = b4.x; sB[kb][nb + 1] = b4.y;
      sB[kb][nb + 2] = b4.z; sB[kb][nb + 3] = b4.w;
    }
    __syncthreads();
#pragma unroll
    for (int k = 0; k < 16; k++) {
      float ar[4], br[4];
#pragma unroll
      for (int i = 0; i < 4; i++) { ar[i] = sA[k][ty * 4 + i]; br[i] = sB[k][tx * 4 + i]; }
#pragma unroll
      for (int i = 0; i < 4; i++)
#pragma unroll
        for (int j = 0; j < 4; j++) acc[i][j] = fmaf(ar[i], br[j], acc[i][j]);
    }
  }
#pragma unroll
  for (int i = 0; i < 4; i++)
#pragma unroll
    for (int j = 0; j < 4; j++)
      p.hkeys[(size_t)(row0 + ty * 4 + i) * 512 + col0 + tx * 4 + j] = __float2half(acc[i][j]);
}

// ---------------- prep: repack weights + zero state/barrier + mask ----------------
__global__ __launch_bounds__(256) void k_repack(Params p) {
  const int gsz = gridDim.x * 256;
  const int t0 = blockIdx.x * 256 + threadIdx.x;
  // gw1T[r:1280][u:512] -> 4 halfs {wr,wz,wn,0}
  for (int i = t0; i < 1280 * 512; i += gsz) {
    int r = i >> 9, u = i & 511;
    const float* src = (r < 768) ? p.attn_wi + (size_t)r * 1536 : p.attn_wh + (size_t)(r - 768) * 1536;
    __half2* d = (__half2*)(p.gw1T + ((size_t)i << 2));
    d[0] = __halves2half2(__float2half(src[u]), __float2half(src[512 + u]));
    d[1] = __halves2half2(__float2half(src[1024 + u]), __float2half(0.f));
  }
  // gw2T[r:1536][u:512]
  for (int i = t0; i < 1536 * 512; i += gsz) {
    int r = i >> 9, u = i & 511;
    const float* src = (r < 1024) ? p.out_wi + (size_t)r * 1536 : p.out_wh + (size_t)(r - 1024) * 1536;
    __half2* d = (__half2*)(p.gw2T + ((size_t)i << 2));
    d[0] = __halves2half2(__float2half(src[u]), __float2half(src[512 + u]));
    d[1] = __halves2half2(__float2half(src[1024 + u]), __float2half(0.f));
  }
  // decT[m][k]
  for (int i = t0; i < 1024 * 128; i += gsz) {
    int k = i >> 7, m = i & 127;
    p.decT[(size_t)m * 1024 + k] = __float2half(p.dec_w[(size_t)k * 128 + m]);
  }
  for (int i = t0; i < 1024; i += gsz) p.gateh[i] = __float2half(p.gate_w[i]);
  for (int i = t0; i < 16384; i += gsz) p.locwh[i] = __float2half(p.loc_w[i]);
  // pre1T[pc][m]
  for (int i = t0; i < 128 * 256; i += gsz) {
    int m = i >> 8, pc = i & 255;
    p.pre1T[(size_t)pc * 128 + m] = __float2half(p.pre_w1[(size_t)m * 256 + pc]);
  }
  // pre2T[pc][k]
  for (int i = t0; i < 256 * 256; i += gsz) {
    int k = i >> 8, pc = i & 255;
    p.pre2T[(size_t)pc * 256 + k] = __float2half(p.pre_w2[(size_t)k * 256 + pc]);
  }
  for (int i = t0; i < 122880; i += gsz) p.stateZ[i] = 0.f;
  if (t0 < 8) { p.barc[t0] = 0u; }
  for (int i = t0; i < 12800; i += gsz) {
    int b = i / 400, t = i - b * 400;
    p.out_mask[i] = (t > p.mel_lens[b]) ? 1.f : 0.f;
  }
}

struct SMemMega {
  union {
    struct { float x[4][1536]; float part[16][256]; float gsum[256]; } gr;
    struct { float locS[64][33]; float aw[94]; float ac[94]; float hA_s[512]; float qS[512];
             float cpred[8][512]; float eS[64]; } s3;
    struct { float xh[1024]; float red[1024]; float mel[128]; float p1[256]; } s6;
  } u;
};

// ---------------- GRU stage: block = (bg of 4 b) x (ug of 16 u), full K ----------------
template <int DA, int DX, int DXI>
__device__ __forceinline__ void gru_stage(SMemMega& sm, const __half* wTh,
    const float* __restrict__ xa, const float* __restrict__ xb, const float* __restrict__ hp,
    const float* __restrict__ bi, const float* __restrict__ bh,
    float* __restrict__ hnext, int ug, int b0, int tid) {
  // stage x = [xa | xb | hp] for 4 batches
  for (int b2 = 0; b2 < 4; b2++) {
    int bb = b0 + b2;
    for (int r = tid; r < DX; r += NTHR) {
      float v;
      if (r < DA) v = lda(xa + (size_t)bb * DA + r);
      else if (r < DA + 512) v = lda(xb + ((size_t)bb << 9) + r - DA);
      else v = lda(hp + ((size_t)bb << 9) + r - DA - 512);
      sm.u.gr.x[b2][r] = v;
    }
  }
  __syncthreads();
  const int u = tid & 15, b2 = (tid >> 4) & 3, ks = tid >> 6;
  const int uG = (ug << 4) + u;
  constexpr int RPK = DX >> 4;
  float ar = 0.f, az = 0.f, ani = 0.f, anh = 0.f;
  const uint2* w = (const uint2*)wTh + (size_t)(ks * RPK) * 512 + uG;
#pragma unroll 8
  for (int j = 0; j < RPK; j++) {
    uint2 wv = w[(size_t)j * 512];
    int r = ks * RPK + j;
    float x = sm.u.gr.x[b2][r];
    float2 f0 = cvt2(wv.x);
    float2 f1 = cvt2(wv.y);
    ar = fmaf(x, f0.x, ar);
    az = fmaf(x, f0.y, az);
    float t = x * f1.x;
    if (r < DXI) ani += t; else anh += t;
  }
  ((float4*)sm.u.gr.part)[ks * 64 + u * 4 + b2] = make_float4(ar, az, ani, anh);
  __syncthreads();
  if (tid < 256) {
    float s = 0.f;
#pragma unroll
    for (int l = 0; l < 16; l++) s += sm.u.gr.part[l][tid];
    sm.u.gr.gsum[tid] = s;
  }
  __syncthreads();
  if (tid < 64) {
    int uu = tid & 15, bb2 = tid >> 4;
    int uGf = (ug << 4) + uu;
    const float* g = &sm.u.gr.gsum[(uu * 4 + bb2) * 4];
    float r = fast_sigmoid(g[0] + bi[uGf] + bh[uGf]);
    float z = fast_sigmoid(g[1] + bi[512 + uGf] + bh[512 + uGf]);
    float n = fast_tanh(g[2] + bi[1024 + uGf] + r * (g[3] + bh[1024 + uGf]));
    float hv = sm.u.gr.x[bb2][DXI + uGf];
    sta(&hnext[((size_t)(b0 + bb2) << 9) + uGf], (1.f - z) * n + z * hv);
  }
  __syncthreads();
}

__global__ __launch_bounds__(NTHR) void mega(Params p) {
  __shared__ SMemMega sm;
  const int blk = blockIdx.x, tid = threadIdx.x;
  const int ug = blk & 31, bg = blk >> 5, b0 = bg * 4;  // GRU mapping (ug spreads over XCDs)
  unsigned epoch = 0;
  unsigned* barc = p.barc;
  unsigned* barg = p.barc + 4;

#pragma clang loop unroll(disable)
  for (int step = 0; step < 400; step++) {
    const int par = step & 1;
    float* hA_prev = p.hA + par * 16384;
    float* hA_next = p.hA + (par ^ 1) * 16384;
    float* hO_prev = p.hO + par * 16384;
    float* hO_next = p.hO + (par ^ 1) * 16384;

    // ---- S1: GRU1 ----
    gru_stage<256, 1280, 768>(sm, p.gw1T, p.decin, p.ctx, hA_prev,
                              p.attn_bi, p.attn_bh, hA_next, ug, b0, tid);
    gbar(barc, barg, &epoch);

    // ---- S3: q + conv + loc-proj + tanh + score + e + ctx-partials ----
    {
      const int b = blk >> 3, t8 = blk & 7, t0g = t8 << 6;
      const int tlen = p.text_lens[b];
      for (int j = tid; j < 94; j += NTHR) {
        int pp = t0g - 15 + j;
        bool ok = (unsigned)pp < 512u;
        sm.u.s3.aw[j] = ok ? lda(&p.attw[(b << 9) + pp]) : 0.f;
        sm.u.s3.ac[j] = ok ? lda(&p.attcum[(b << 9) + pp]) : 0.f;
      }
      if (tid < 512) sm.u.s3.hA_s[tid] = lda(&hA_next[(b << 9) + tid]);
      __syncthreads();
      // conv -> locS
      for (int i = tid; i < 2048; i += NTHR) {
        int tt = i >> 5, f = i & 31;
        const float* w0 = p.conv_w + f * 62;
        float a = 0.f;
#pragma unroll
        for (int k = 0; k < 31; k++)
          a = fmaf(w0[k], sm.u.s3.aw[tt + k], fmaf(w0[31 + k], sm.u.s3.ac[tt + k], a));
        sm.u.s3.locS[tt][f] = a;
      }
      // q partials: fp32 q_w [k][512], thread = (ah: 2 cols, ks: 4 slices of 128 k)
      {
        int ah = tid & 255, ks4 = tid >> 8;
        const float2* qw = (const float2*)p.q_w + ah;
        float q0 = 0.f, q1 = 0.f;
#pragma unroll 8
        for (int k = ks4 * 128; k < ks4 * 128 + 128; k++) {
          float2 w = qw[(size_t)k * 256];
          float x = sm.u.s3.hA_s[k];
          q0 = fmaf(x, w.x, q0); q1 = fmaf(x, w.y, q1);
        }
        sm.u.s3.cpred[ks4][ah * 2] = q0;
        sm.u.s3.cpred[ks4][ah * 2 + 1] = q1;
      }
      __syncthreads();
      if (tid < 512)
        sm.u.s3.qS[tid] = sm.u.s3.cpred[0][tid] + sm.u.s3.cpred[1][tid] +
                          sm.u.s3.cpred[2][tid] + sm.u.s3.cpred[3][tid] + p.loc_b[tid];
      __syncthreads();
      // scoring: 16 waves x 4 t
      const int lane = tid & 63, wv = tid >> 6;
      float acc[4][8];
      float4 qA = *(const float4*)&sm.u.s3.qS[lane * 8];
      float4 qB = *(const float4*)&sm.u.s3.qS[lane * 8 + 4];
#pragma unroll
      for (int j = 0; j < 4; j++) {
        int t = t0g + wv * 4 + j;
        HU4 raw; raw.u = *(const uint4*)(p.hkeys + (((size_t)(b << 9) + t) << 9) + lane * 8);
        float2 k0 = __half22float2(raw.h[0]), k1 = __half22float2(raw.h[1]);
        float2 k2 = __half22float2(raw.h[2]), k3 = __half22float2(raw.h[3]);
        acc[j][0] = qA.x + k0.x; acc[j][1] = qA.y + k0.y;
        acc[j][2] = qA.z + k1.x; acc[j][3] = qA.w + k1.y;
        acc[j][4] = qB.x + k2.x; acc[j][5] = qB.y + k2.y;
        acc[j][6] = qB.z + k3.x; acc[j][7] = qB.w + k3.y;
      }
#pragma unroll 4
      for (int f = 0; f < 32; f++) {
        HU4 rw; rw.u = *(const uint4*)(p.locwh + (size_t)f * 512 + lane * 8);
        float2 w0 = __half22float2(rw.h[0]), w1 = __half22float2(rw.h[1]);
        float2 w2 = __half22float2(rw.h[2]), w3 = __half22float2(rw.h[3]);
#pragma unroll
        for (int j = 0; j < 4; j++) {
          float lf = sm.u.s3.locS[wv * 4 + j][f];
          acc[j][0] = fmaf(lf, w0.x, acc[j][0]); acc[j][1] = fmaf(lf, w0.y, acc[j][1]);
          acc[j][2] = fmaf(lf, w1.x, acc[j][2]); acc[j][3] = fmaf(lf, w1.y, acc[j][3]);
          acc[j][4] = fmaf(lf, w2.x, acc[j][4]); acc[j][5] = fmaf(lf, w2.y, acc[j][5]);
          acc[j][6] = fmaf(lf, w3.x, acc[j][6]); acc[j][7] = fmaf(lf, w3.y, acc[j][7]);
        }
      }
      float4 sA = *(const float4*)(p.score_w + lane * 8);
      float4 sB = *(const float4*)(p.score_w + lane * 8 + 4);
      float sbias = p.score_b[0];
      float e_reg[4];
#pragma unroll
      for (int j = 0; j < 4; j++) {
        float pv = fast_tanh(acc[j][0]) * sA.x + fast_tanh(acc[j][1]) * sA.y +
                   fast_tanh(acc[j][2]) * sA.z + fast_tanh(acc[j][3]) * sA.w +
                   fast_tanh(acc[j][4]) * sB.x + fast_tanh(acc[j][5]) * sB.y +
                   fast_tanh(acc[j][6]) * sB.z + fast_tanh(acc[j][7]) * sB.w;
#pragma unroll
        for (int off = 32; off > 0; off >>= 1) pv += __shfl_xor(pv, off, 64);
        int t = t0g + wv * 4 + j;
        e_reg[j] = (t > tlen) ? 0.f : __expf(pv + sbias);
      }
      if (lane == 0) {
#pragma unroll
        for (int j = 0; j < 4; j++) sm.u.s3.eS[wv * 4 + j] = e_reg[j];
      }
      // ctx partials
      float cp[8] = {0.f, 0.f, 0.f, 0.f, 0.f, 0.f, 0.f, 0.f};
#pragma unroll
      for (int j = 0; j < 4; j++) {
        int t = t0g + wv * 4 + j;
        HU4 raw; raw.u = *(const uint4*)(p.hkeys + (((size_t)(b << 9) + t) << 9) + lane * 8);
        float2 k0 = __half22float2(raw.h[0]), k1 = __half22float2(raw.h[1]);
        float2 k2 = __half22float2(raw.h[2]), k3 = __half22float2(raw.h[3]);
        float e = e_reg[j];
        cp[0] = fmaf(e, k0.x, cp[0]); cp[1] = fmaf(e, k0.y, cp[1]);
        cp[2] = fmaf(e, k1.x, cp[2]); cp[3] = fmaf(e, k1.y, cp[3]);
        cp[4] = fmaf(e, k2.x, cp[4]); cp[5] = fmaf(e, k2.y, cp[5]);
        cp[6] = fmaf(e, k3.x, cp[6]); cp[7] = fmaf(e, k3.y, cp[7]);
      }
      __syncthreads();
      if (wv < 8) {
        float4* r0 = (float4*)&sm.u.s3.cpred[wv][lane * 8];
        r0[0] = make_float4(cp[0], cp[1], cp[2], cp[3]);
        r0[1] = make_float4(cp[4], cp[5], cp[6], cp[7]);
      }
      __syncthreads();
      if (wv >= 8) {
        float* r0 = &sm.u.s3.cpred[wv - 8][lane * 8];
#pragma unroll
        for (int i = 0; i < 8; i++) r0[i] += cp[i];
      }
      __syncthreads();
      if (tid < 512) {
        float s = 0.f;
#pragma unroll
        for (int j = 0; j < 8; j++) s += sm.u.s3.cpred[j][tid];
        sta(&p.ctxp[(size_t)((b << 3) + t8) * 512 + tid], s);
      }
      if (tid < 64) {
        float e = sm.u.s3.eS[tid];
        sta(&p.ebuf[(b << 9) + t0g + tid], e);
        float z = e;
#pragma unroll
        for (int off = 32; off > 0; off >>= 1) z += __shfl_xor(z, off, 64);
        if (tid == 0) sta(&p.zpart[b * 8 + t8], z);
      }
    }
    gbar(barc, barg, &epoch);

    // ---- S4: normalize -> ctx, attw, attcum, out_attn ----
    {
      const int b = blk >> 3, ch = blk & 7;
      if (tid < 128) {
        float Z = 0.f;
#pragma unroll
        for (int j = 0; j < 8; j++) Z += lda(&p.zpart[b * 8 + j]);
        float invZ = fast_rcp(Z);
        if (tid < 64) {
          int a = (ch << 6) + tid;
          float s = 0.f;
#pragma unroll
          for (int j = 0; j < 8; j++) s += lda(&p.ctxp[(size_t)((b << 3) + j) * 512 + a]);
          sta(&p.ctx[(b << 9) + a], s * invZ);
        } else {
          int t = (ch << 6) + (tid - 64);
          float v = lda(&p.ebuf[(b << 9) + t]) * invZ;
          sta(&p.attw[(b << 9) + t], v);
          float oc = lda(&p.attcum[(b << 9) + t]);
          sta(&p.attcum[(b << 9) + t], oc + v);
          p.out_attn[(size_t)b * 204800 + (size_t)step * 512 + t] = v;
        }
      }
    }
    gbar(barc, barg, &epoch);

    // ---- S5: GRU2 ----
    gru_stage<512, 1536, 1024>(sm, p.gw2T, hA_next, p.ctx, hO_prev,
                               p.out_bi, p.out_bh, hO_next, ug, b0, tid);
    gbar(barc, barg, &epoch);

    // ---- S6: mel/gate + prenet (32 b-blocks) ----
    if (blk < 32) {
      const int b = blk;
      sm.u.s6.xh[tid] = (tid < 512) ? lda(&hO_next[(b << 9) + tid])
                                    : lda(&p.ctx[(b << 9) + tid - 512]);
      __syncthreads();
      bool masked = step > p.mel_lens[b];
      {
        int m = tid & 127, ks = tid >> 7;
        const HU4* dp = (const HU4*)(p.decT + (size_t)m * 1024 + ks * 128);
        float a = 0.f;
#pragma unroll 4
        for (int it = 0; it < 16; it++) {
          HU4 raw = dp[it];
          int kb = ks * 128 + it * 8;
#pragma unroll
          for (int h2 = 0; h2 < 4; h2++) {
            float2 w = __half22float2(raw.h[h2]);
            a = fmaf(sm.u.s6.xh[kb + h2 * 2], w.x, a);
            a = fmaf(sm.u.s6.xh[kb + h2 * 2 + 1], w.y, a);
          }
        }
        sm.u.s6.red[tid] = a;
      }
      __syncthreads();
      if (tid < 128) {
        float mv = p.dec_b[tid];
#pragma unroll
        for (int j = 0; j < 8; j++) mv += sm.u.s6.red[tid + j * 128];
        sm.u.s6.mel[tid] = mv;
        p.out_mel[(size_t)b * 51200 + (size_t)step * 128 + tid] = masked ? 0.f : mv;
      }
      __syncthreads();
      sm.u.s6.red[tid] = sm.u.s6.xh[tid] * __half2float(p.gateh[tid]);
      __syncthreads();
      if (tid < 64) {
        float g = 0.f;
#pragma unroll
        for (int j = 0; j < 16; j++) g += sm.u.s6.red[tid + j * 64];
#pragma unroll
        for (int off = 32; off > 0; off >>= 1) g += __shfl_xor(g, off, 64);
        if (tid == 0) p.out_gate[b * 400 + step] = masked ? 1000.f : (g + p.gate_b[0]);
      }
      __syncthreads();
      {
        int pc = tid & 255, ks = tid >> 8;
        const HU4* wp = (const HU4*)(p.pre1T + (size_t)pc * 128 + ks * 32);
        float a = 0.f;
#pragma unroll
        for (int it = 0; it < 4; it++) {
          HU4 raw = wp[it];
          int kb = ks * 32 + it * 8;
#pragma unroll
          for (int h2 = 0; h2 < 4; h2++) {
            float2 w = __half22float2(raw.h[h2]);
            a = fmaf(sm.u.s6.mel[kb + h2 * 2], w.x, a);
            a = fmaf(sm.u.s6.mel[kb + h2 * 2 + 1], w.y, a);
          }
        }
        sm.u.s6.red[tid] = a;
      }
      __syncthreads();
      if (tid < 256) {
        float a = sm.u.s6.red[tid] + sm.u.s6.red[tid + 256] + sm.u.s6.red[tid + 512] + sm.u.s6.red[tid + 768];
        sm.u.s6.p1[tid] = fmaxf(a, 0.f);
      }
      __syncthreads();
      {
        int pc = tid & 255, ks = tid >> 8;
        const HU4* wp = (const HU4*)(p.pre2T + (size_t)pc * 256 + ks * 64);
        float a = 0.f;
#pragma unroll
        for (int it = 0; it < 8; it++) {
          HU4 raw = wp[it];
          int kb = ks * 64 + it * 8;
#pragma unroll
          for (int h2 = 0; h2 < 4; h2++) {
            float2 w = __half22float2(raw.h[h2]);
            a = fmaf(sm.u.s6.p1[kb + h2 * 2], w.x, a);
            a = fmaf(sm.u.s6.p1[kb + h2 * 2 + 1], w.y, a);
          }
        }
        sm.u.s6.red[tid] = a;
      }
      __syncthreads();
      if (tid < 256) {
        float a = sm.u.s6.red[tid] + sm.u.s6.red[tid + 256] + sm.u.s6.red[tid + 512] + sm.u.s6.red[tid + 768];
        sta(&p.decin[(b << 8) + tid], fmaxf(a, 0.f));
      }
    }
    gbar(barc, barg, &epoch);
  }
}

extern "C" void kernel_launch(void* const* d_in, const int* in_sizes, int n_in,
                              void* d_out, int out_size, void* d_ws, size_t ws_size,
                              hipStream_t stream) {
  Params p;
  p.enc       = (const float*)d_in[0];
  p.text_lens = (const int*)d_in[2];
  p.mel_lens  = (const int*)d_in[3];
  p.pre_w1    = (const float*)d_in[5];
  p.pre_w2    = (const float*)d_in[6];
  p.attn_wi   = (const float*)d_in[7];
  p.attn_wh   = (const float*)d_in[8];
  p.attn_bi   = (const float*)d_in[9];
  p.attn_bh   = (const float*)d_in[10];
  p.q_w       = (const float*)d_in[11];
  p.k_w       = (const float*)d_in[12];
  p.score_w   = (const float*)d_in[13];
  p.score_b   = (const float*)d_in[14];
  p.conv_w    = (const float*)d_in[15];
  p.loc_w     = (const float*)d_in[16];
  p.loc_b     = (const float*)d_in[17];
  p.out_wi    = (const float*)d_in[18];
  p.out_wh    = (const float*)d_in[19];
  p.out_bi    = (const float*)d_in[20];
  p.out_bh    = (const float*)d_in[21];
  p.dec_w     = (const float*)d_in[22];
  p.dec_b     = (const float*)d_in[23];
  p.gate_w    = (const float*)d_in[24];
  p.gate_b    = (const float*)d_in[25];

  float* ws = (float*)d_ws;
  p.hkeys  = (__half*)(ws);                    // 8,388,608 halfs
  p.gw1T   = (__half*)(ws + 4194304);          // 2,621,440 halfs
  p.gw2T   = (__half*)(ws + 5505024);          // 3,145,728 halfs
  p.decT   = (__half*)(ws + 7077888);          // 131,072 halfs
  p.pre1T  = (__half*)(ws + 7143424);          // 32,768
  p.pre2T  = (__half*)(ws + 7159808);          // 65,536
  p.gateh  = (__half*)(ws + 7192576);          // 1,024
  p.locwh  = (__half*)(ws + 7193088);          // 16,384
  p.hA     = ws + 7201280;                     // 2 x 16384
  p.hO     = ws + 7234048;                     // 2 x 16384
  p.attw   = ws + 7266816;                     // 16384
  p.attcum = ws + 7283200;                     // 16384
  p.ctx    = ws + 7299584;                     // 16384
  p.decin  = ws + 7315968;                     // 8192
  p.stateZ = p.hA;                             // contiguous zero region 122,880 floats
  p.ebuf   = ws + 7324160;                     // 16384
  p.zpart  = ws + 7340544;                     // 256
  p.ctxp   = ws + 7340800;                     // 131,072
  p.barc   = (unsigned*)(ws + 7471872);        // 8 uints (cnt @0, gen @4)
  float* out = (float*)d_out;
  p.out_mel  = out;
  p.out_gate = out + 1638400;
  p.out_attn = out + 1651200;
  p.out_mask = out + 8204800;

  k_repack<<<2048, 256, 0, stream>>>(p);
  k_keys<<<dim3(128, 8), 512, 0, stream>>>(p);
  void* args[] = { (void*)&p };
  hipLaunchCooperativeKernel((const void*)mega, dim3(NBLK), dim3(NTHR), args, 0, stream);
}

// Round 6
// 54873.859 us; speedup vs baseline: 2.6348x; 1.2527x over previous
//
#include <hip/hip_runtime.h>
#include <hip/hip_fp16.h>
#include <math.h>

#define NBLK 256
#define NTHR 1024

__device__ __forceinline__ float fast_rcp(float x) {
#if __has_builtin(__builtin_amdgcn_rcpf)
  return __builtin_amdgcn_rcpf(x);
#else
  return 1.f / x;
#endif
}
__device__ __forceinline__ float fast_sigmoid(float x) { return fast_rcp(1.f + __expf(-x)); }
__device__ __forceinline__ float fast_tanh(float x) { return 1.f - 2.f * fast_rcp(1.f + __expf(2.f * x)); }

union HU2 { unsigned int u; __half2 h; };
union HU4 { uint4 u; __half2 h[4]; };
__device__ __forceinline__ float2 cvt2(unsigned int u) { HU2 t; t.u = u; return __half22float2(t.h); }

// agent-scope (L2-bypassing) communication primitives
__device__ __forceinline__ void sta(float* p, float v) {
  __hip_atomic_store(p, v, __ATOMIC_RELAXED, __HIP_MEMORY_SCOPE_AGENT);
}
__device__ __forceinline__ float lda(const float* p) {
  return __hip_atomic_load(p, __ATOMIC_RELAXED, __HIP_MEMORY_SCOPE_AGENT);
}

struct Params {
  const float *enc, *pre_w1, *pre_w2, *attn_wi, *attn_wh, *attn_bi, *attn_bh;
  const float *q_w, *k_w, *score_w, *score_b, *conv_w, *loc_w, *loc_b;
  const float *out_wi, *out_wh, *out_bi, *out_bh, *dec_w, *dec_b, *gate_w, *gate_b;
  const int *text_lens, *mel_lens;
  __half *hkeys, *gw1T, *gw2T, *decT, *pre1T, *pre2T, *gateh, *locwh, *qwT;
  float *hA, *hO, *attw, *attcum, *ctx, *decin, *ebuf, *zpart, *ctxp, *stateZ;
  unsigned *barc;
  float *out_mel, *out_gate, *out_attn, *out_mask;
};

// two-level flag barrier: per-block arrive slots (no contention) + one gen dword
__device__ __forceinline__ void gbar(unsigned* flags, unsigned* gen, unsigned e,
                                     int blk, int tid) {
  __syncthreads();
  if (tid == 0) {
    asm volatile("s_waitcnt vmcnt(0) lgkmcnt(0)" ::: "memory");
    __hip_atomic_store(&flags[blk], e, __ATOMIC_RELAXED, __HIP_MEMORY_SCOPE_AGENT);
  }
  if (blk == 0) {
    if (tid < 64) {
      while (true) {
        bool ok = true;
#pragma unroll
        for (int j = 0; j < 4; j++) {
          unsigned v = __hip_atomic_load(&flags[tid * 4 + j], __ATOMIC_RELAXED,
                                         __HIP_MEMORY_SCOPE_AGENT);
          ok &= (v >= e);
        }
        if (__all(ok)) break;
        __builtin_amdgcn_s_sleep(1);
      }
      if (tid == 0)
        __hip_atomic_store(gen, e, __ATOMIC_RELAXED, __HIP_MEMORY_SCOPE_AGENT);
    }
  } else {
    if (tid == 0) {
      while (__hip_atomic_load(gen, __ATOMIC_RELAXED, __HIP_MEMORY_SCOPE_AGENT) < e)
        __builtin_amdgcn_s_sleep(2);
    }
  }
  asm volatile("" ::: "memory");
  __syncthreads();
}

// ---------------- prep: keys GEMM (fp16 out) ----------------
__global__ __launch_bounds__(512) void k_keys(Params p) {
  __shared__ float sA[16][132];
  __shared__ float sB[16][68];
  int tid = threadIdx.x;
  int row0 = blockIdx.x * 128, col0 = blockIdx.y * 64;
  float acc[4][4] = {};
  int r = tid >> 2, kq = tid & 3;
  int tx = tid & 15, ty = tid >> 4;
  for (int k0 = 0; k0 < 1024; k0 += 16) {
    __syncthreads();
    float4 a4 = *(const float4*)(p.enc + (size_t)(row0 + r) * 1024 + k0 + kq * 4);
    sA[kq * 4 + 0][r] = a4.x; sA[kq * 4 + 1][r] = a4.y;
    sA[kq * 4 + 2][r] = a4.z; sA[kq * 4 + 3][r] = a4.w;
    if (tid < 256) {
      int kb = tid >> 4, nb = (tid & 15) * 4;
      float4 b4 = *(const float4*)(p.k_w + (size_t)(k0 + kb) * 512 + col0 + nb);
      sB[kb][nb + 0] = b4.x; sB[kb][nb + 1] = b4.y;
      sB[kb][nb + 2] = b4.z; sB[kb][nb + 3] = b4.w;
    }
    __syncthreads();
#pragma unroll
    for (int k = 0; k < 16; k++) {
      float ar[4], br[4];
#pragma unroll
      for (int i = 0; i < 4; i++) { ar[i] = sA[k][ty * 4 + i]; br[i] = sB[k][tx * 4 + i]; }
#pragma unroll
      for (int i = 0; i < 4; i++)
#pragma unroll
        for (int j = 0; j < 4; j++) acc[i][j] = fmaf(ar[i], br[j], acc[i][j]);
    }
  }
#pragma unroll
  for (int i = 0; i < 4; i++)
#pragma unroll
    for (int j = 0; j < 4; j++)
      p.hkeys[(size_t)(row0 + ty * 4 + i) * 512 + col0 + tx * 4 + j] = __float2half(acc[i][j]);
}

// ---------------- prep: repack weights + zero state/barrier + mask ----------------
__global__ __launch_bounds__(256) void k_repack(Params p) {
  const int gsz = gridDim.x * 256;
  const int t0 = blockIdx.x * 256 + threadIdx.x;
  // gw1T[r:1280][u:512] -> 4 halfs {wr,wz,wn,0}
  for (int i = t0; i < 1280 * 512; i += gsz) {
    int r = i >> 9, u = i & 511;
    const float* src = (r < 768) ? p.attn_wi + (size_t)r * 1536 : p.attn_wh + (size_t)(r - 768) * 1536;
    __half2* d = (__half2*)(p.gw1T + ((size_t)i << 2));
    d[0] = __halves2half2(__float2half(src[u]), __float2half(src[512 + u]));
    d[1] = __halves2half2(__float2half(src[1024 + u]), __float2half(0.f));
  }
  // gw2T[r:1536][u:512]
  for (int i = t0; i < 1536 * 512; i += gsz) {
    int r = i >> 9, u = i & 511;
    const float* src = (r < 1024) ? p.out_wi + (size_t)r * 1536 : p.out_wh + (size_t)(r - 1024) * 1536;
    __half2* d = (__half2*)(p.gw2T + ((size_t)i << 2));
    d[0] = __halves2half2(__float2half(src[u]), __float2half(src[512 + u]));
    d[1] = __halves2half2(__float2half(src[1024 + u]), __float2half(0.f));
  }
  // qwT[a][k] fp16
  for (int i = t0; i < 512 * 512; i += gsz) {
    int k = i >> 9, a = i & 511;
    p.qwT[(size_t)a * 512 + k] = __float2half(p.q_w[(size_t)k * 512 + a]);
  }
  // decT[m][k]
  for (int i = t0; i < 1024 * 128; i += gsz) {
    int k = i >> 7, m = i & 127;
    p.decT[(size_t)m * 1024 + k] = __float2half(p.dec_w[(size_t)k * 128 + m]);
  }
  for (int i = t0; i < 1024; i += gsz) p.gateh[i] = __float2half(p.gate_w[i]);
  for (int i = t0; i < 16384; i += gsz) p.locwh[i] = __float2half(p.loc_w[i]);
  // pre1T[pc][m]
  for (int i = t0; i < 128 * 256; i += gsz) {
    int m = i >> 8, pc = i & 255;
    p.pre1T[(size_t)pc * 128 + m] = __float2half(p.pre_w1[(size_t)m * 256 + pc]);
  }
  // pre2T[pc][k]
  for (int i = t0; i < 256 * 256; i += gsz) {
    int k = i >> 8, pc = i & 255;
    p.pre2T[(size_t)pc * 256 + k] = __float2half(p.pre_w2[(size_t)k * 256 + pc]);
  }
  for (int i = t0; i < 122880; i += gsz) p.stateZ[i] = 0.f;
  for (int i = t0; i < 512; i += gsz) p.barc[i] = 0u;
  for (int i = t0; i < 12800; i += gsz) {
    int b = i / 400, t = i - b * 400;
    p.out_mask[i] = (t > p.mel_lens[b]) ? 1.f : 0.f;
  }
}

struct SMemMega {
  union {
    struct { float x[4][1536]; float part[16][256]; float gsum[256]; } gr;
    struct { float locS[64][33]; float aw[94]; float ac[94]; float hA_s[512]; float qS[512];
             float cpred[8][512]; float eS[64]; } s3;
    struct { float xh[1024]; float red[1024]; float mel[128]; float p1[256]; } s6;
  } u;
};

// ---------------- GRU stage: block = (bg of 4 b) x (ug of 16 u), full K ----------------
template <int DA, int DX, int DXI>
__device__ __forceinline__ void gru_stage(SMemMega& sm, const __half* wTh,
    const float* __restrict__ xa, const float* __restrict__ xb, const float* __restrict__ hp,
    const float* __restrict__ bi, const float* __restrict__ bh,
    float* __restrict__ hnext, int ug, int b0, int tid) {
  for (int b2 = 0; b2 < 4; b2++) {
    int bb = b0 + b2;
    for (int r = tid; r < DX; r += NTHR) {
      float v;
      if (r < DA) v = lda(xa + (size_t)bb * DA + r);
      else if (r < DA + 512) v = lda(xb + ((size_t)bb << 9) + r - DA);
      else v = lda(hp + ((size_t)bb << 9) + r - DA - 512);
      sm.u.gr.x[b2][r] = v;
    }
  }
  __syncthreads();
  const int u = tid & 15, b2 = (tid >> 4) & 3, ks = tid >> 6;
  const int uG = (ug << 4) + u;
  constexpr int RPK = DX >> 4;
  float ar = 0.f, az = 0.f, ani = 0.f, anh = 0.f;
  const uint2* w = (const uint2*)wTh + (size_t)(ks * RPK) * 512 + uG;
#pragma unroll 8
  for (int j = 0; j < RPK; j++) {
    uint2 wv = w[(size_t)j * 512];
    int r = ks * RPK + j;
    float x = sm.u.gr.x[b2][r];
    float2 f0 = cvt2(wv.x);
    float2 f1 = cvt2(wv.y);
    ar = fmaf(x, f0.x, ar);
    az = fmaf(x, f0.y, az);
    float t = x * f1.x;
    if (r < DXI) ani += t; else anh += t;
  }
  ((float4*)sm.u.gr.part)[ks * 64 + u * 4 + b2] = make_float4(ar, az, ani, anh);
  __syncthreads();
  if (tid < 256) {
    float s = 0.f;
#pragma unroll
    for (int l = 0; l < 16; l++) s += sm.u.gr.part[l][tid];
    sm.u.gr.gsum[tid] = s;
  }
  __syncthreads();
  if (tid < 64) {
    int uu = tid & 15, bb2 = tid >> 4;
    int uGf = (ug << 4) + uu;
    const float* g = &sm.u.gr.gsum[(uu * 4 + bb2) * 4];
    float r = fast_sigmoid(g[0] + bi[uGf] + bh[uGf]);
    float z = fast_sigmoid(g[1] + bi[512 + uGf] + bh[512 + uGf]);
    float n = fast_tanh(g[2] + bi[1024 + uGf] + r * (g[3] + bh[1024 + uGf]));
    float hv = sm.u.gr.x[bb2][DXI + uGf];
    sta(&hnext[((size_t)(b0 + bb2) << 9) + uGf], (1.f - z) * n + z * hv);
  }
  __syncthreads();
}

__global__ __launch_bounds__(NTHR) void mega(Params p) {
  __shared__ SMemMega sm;
  const int blk = blockIdx.x, tid = threadIdx.x;
  const int ug = blk & 31, bg = blk >> 5, b0 = bg * 4;  // GRU mapping
  unsigned epoch = 0;
  unsigned* flags = p.barc;
  unsigned* gen = p.barc + 384;

#pragma clang loop unroll(disable)
  for (int step = 0; step < 400; step++) {
    const int par = step & 1;
    float* hA_prev = p.hA + par * 16384;
    float* hA_next = p.hA + (par ^ 1) * 16384;
    float* hO_prev = p.hO + par * 16384;
    float* hO_next = p.hO + (par ^ 1) * 16384;

    // ---- S1: GRU1 ----
    gru_stage<256, 1280, 768>(sm, p.gw1T, p.decin, p.ctx, hA_prev,
                              p.attn_bi, p.attn_bh, hA_next, ug, b0, tid);
    gbar(flags, gen, ++epoch, blk, tid);

    // ---- S3: q + conv + loc-proj + tanh + score + e + ctx-partials ----
    // b = blk & 31 pins all 8 t-tiles of a batch to one XCD (keys L2-resident)
    {
      const int b = blk & 31, t8 = blk >> 5, t0g = t8 << 6;
      const int tlen = p.text_lens[b];
      for (int j = tid; j < 94; j += NTHR) {
        int pp = t0g - 15 + j;
        bool ok = (unsigned)pp < 512u;
        sm.u.s3.aw[j] = ok ? lda(&p.attw[(b << 9) + pp]) : 0.f;
        sm.u.s3.ac[j] = ok ? lda(&p.attcum[(b << 9) + pp]) : 0.f;
      }
      if (tid < 512) sm.u.s3.hA_s[tid] = lda(&hA_next[(b << 9) + tid]);
      __syncthreads();
      // conv -> locS
      for (int i = tid; i < 2048; i += NTHR) {
        int tt = i >> 5, f = i & 31;
        const float* w0 = p.conv_w + f * 62;
        float a = 0.f;
#pragma unroll
        for (int k = 0; k < 31; k++)
          a = fmaf(w0[k], sm.u.s3.aw[tt + k], fmaf(w0[31 + k], sm.u.s3.ac[tt + k], a));
        sm.u.s3.locS[tt][f] = a;
      }
      // q partials: fp16 qwT[a][k], 2 k-slices
      {
        int a = tid & 511, ks = tid >> 9;
        const HU4* qp = (const HU4*)(p.qwT + (size_t)a * 512 + ks * 256);
        float q0 = 0.f, q1 = 0.f;
#pragma unroll 4
        for (int it = 0; it < 32; it++) {
          HU4 raw = qp[it];
          int kb = ks * 256 + it * 8;
#pragma unroll
          for (int h2 = 0; h2 < 4; h2++) {
            float2 w = __half22float2(raw.h[h2]);
            q0 = fmaf(sm.u.s3.hA_s[kb + h2 * 2], w.x, q0);
            q1 = fmaf(sm.u.s3.hA_s[kb + h2 * 2 + 1], w.y, q1);
          }
        }
        sm.u.s3.cpred[ks][a] = q0 + q1;
      }
      __syncthreads();
      if (tid < 512)
        sm.u.s3.qS[tid] = sm.u.s3.cpred[0][tid] + sm.u.s3.cpred[1][tid] + p.loc_b[tid];
      __syncthreads();
      // scoring: 16 waves x 4 t
      const int lane = tid & 63, wv = tid >> 6;
      float acc[4][8];
      float4 qA = *(const float4*)&sm.u.s3.qS[lane * 8];
      float4 qB = *(const float4*)&sm.u.s3.qS[lane * 8 + 4];
#pragma unroll
      for (int j = 0; j < 4; j++) {
        int t = t0g + wv * 4 + j;
        HU4 raw; raw.u = *(const uint4*)(p.hkeys + (((size_t)(b << 9) + t) << 9) + lane * 8);
        float2 k0 = __half22float2(raw.h[0]), k1 = __half22float2(raw.h[1]);
        float2 k2 = __half22float2(raw.h[2]), k3 = __half22float2(raw.h[3]);
        acc[j][0] = qA.x + k0.x; acc[j][1] = qA.y + k0.y;
        acc[j][2] = qA.z + k1.x; acc[j][3] = qA.w + k1.y;
        acc[j][4] = qB.x + k2.x; acc[j][5] = qB.y + k2.y;
        acc[j][6] = qB.z + k3.x; acc[j][7] = qB.w + k3.y;
      }
#pragma unroll 4
      for (int f = 0; f < 32; f++) {
        HU4 rw; rw.u = *(const uint4*)(p.locwh + (size_t)f * 512 + lane * 8);
        float2 w0 = __half22float2(rw.h[0]), w1 = __half22float2(rw.h[1]);
        float2 w2 = __half22float2(rw.h[2]), w3 = __half22float2(rw.h[3]);
#pragma unroll
        for (int j = 0; j < 4; j++) {
          float lf = sm.u.s3.locS[wv * 4 + j][f];
          acc[j][0] = fmaf(lf, w0.x, acc[j][0]); acc[j][1] = fmaf(lf, w0.y, acc[j][1]);
          acc[j][2] = fmaf(lf, w1.x, acc[j][2]); acc[j][3] = fmaf(lf, w1.y, acc[j][3]);
          acc[j][4] = fmaf(lf, w2.x, acc[j][4]); acc[j][5] = fmaf(lf, w2.y, acc[j][5]);
          acc[j][6] = fmaf(lf, w3.x, acc[j][6]); acc[j][7] = fmaf(lf, w3.y, acc[j][7]);
        }
      }
      float4 sA = *(const float4*)(p.score_w + lane * 8);
      float4 sB = *(const float4*)(p.score_w + lane * 8 + 4);
      float sbias = p.score_b[0];
      float e_reg[4];
#pragma unroll
      for (int j = 0; j < 4; j++) {
        float pv = fast_tanh(acc[j][0]) * sA.x + fast_tanh(acc[j][1]) * sA.y +
                   fast_tanh(acc[j][2]) * sA.z + fast_tanh(acc[j][3]) * sA.w +
                   fast_tanh(acc[j][4]) * sB.x + fast_tanh(acc[j][5]) * sB.y +
                   fast_tanh(acc[j][6]) * sB.z + fast_tanh(acc[j][7]) * sB.w;
#pragma unroll
        for (int off = 32; off > 0; off >>= 1) pv += __shfl_xor(pv, off, 64);
        int t = t0g + wv * 4 + j;
        e_reg[j] = (t > tlen) ? 0.f : __expf(pv + sbias);
      }
      if (lane == 0) {
#pragma unroll
        for (int j = 0; j < 4; j++) sm.u.s3.eS[wv * 4 + j] = e_reg[j];
      }
      // ctx partials (keys L2-hot re-read)
      float cp[8] = {0.f, 0.f, 0.f, 0.f, 0.f, 0.f, 0.f, 0.f};
#pragma unroll
      for (int j = 0; j < 4; j++) {
        int t = t0g + wv * 4 + j;
        HU4 raw; raw.u = *(const uint4*)(p.hkeys + (((size_t)(b << 9) + t) << 9) + lane * 8);
        float2 k0 = __half22float2(raw.h[0]), k1 = __half22float2(raw.h[1]);
        float2 k2 = __half22float2(raw.h[2]), k3 = __half22float2(raw.h[3]);
        float e = e_reg[j];
        cp[0] = fmaf(e, k0.x, cp[0]); cp[1] = fmaf(e, k0.y, cp[1]);
        cp[2] = fmaf(e, k1.x, cp[2]); cp[3] = fmaf(e, k1.y, cp[3]);
        cp[4] = fmaf(e, k2.x, cp[4]); cp[5] = fmaf(e, k2.y, cp[5]);
        cp[6] = fmaf(e, k3.x, cp[6]); cp[7] = fmaf(e, k3.y, cp[7]);
      }
      __syncthreads();
      if (wv < 8) {
        float4* r0 = (float4*)&sm.u.s3.cpred[wv][lane * 8];
        r0[0] = make_float4(cp[0], cp[1], cp[2], cp[3]);
        r0[1] = make_float4(cp[4], cp[5], cp[6], cp[7]);
      }
      __syncthreads();
      if (wv >= 8) {
        float* r0 = &sm.u.s3.cpred[wv - 8][lane * 8];
#pragma unroll
        for (int i = 0; i < 8; i++) r0[i] += cp[i];
      }
      __syncthreads();
      if (tid < 512) {
        float s = 0.f;
#pragma unroll
        for (int j = 0; j < 8; j++) s += sm.u.s3.cpred[j][tid];
        sta(&p.ctxp[(size_t)((b << 3) + t8) * 512 + tid], s);
      }
      if (tid < 64) {
        float e = sm.u.s3.eS[tid];
        sta(&p.ebuf[(b << 9) + t0g + tid], e);
        float z = e;
#pragma unroll
        for (int off = 32; off > 0; off >>= 1) z += __shfl_xor(z, off, 64);
        if (tid == 0) sta(&p.zpart[b * 8 + t8], z);
      }
    }
    gbar(flags, gen, ++epoch, blk, tid);

    // ---- S4: normalize -> ctx, attw, attcum, out_attn ----
    {
      const int b = blk & 31, ch = blk >> 5;
      if (tid < 128) {
        float Z = 0.f;
#pragma unroll
        for (int j = 0; j < 8; j++) Z += lda(&p.zpart[b * 8 + j]);
        float invZ = fast_rcp(Z);
        if (tid < 64) {
          int a = (ch << 6) + tid;
          float s = 0.f;
#pragma unroll
          for (int j = 0; j < 8; j++) s += lda(&p.ctxp[(size_t)((b << 3) + j) * 512 + a]);
          sta(&p.ctx[(b << 9) + a], s * invZ);
        } else {
          int t = (ch << 6) + (tid - 64);
          float v = lda(&p.ebuf[(b << 9) + t]) * invZ;
          sta(&p.attw[(b << 9) + t], v);
          float oc = lda(&p.attcum[(b << 9) + t]);
          sta(&p.attcum[(b << 9) + t], oc + v);
          p.out_attn[(size_t)b * 204800 + (size_t)step * 512 + t] = v;
        }
      }
    }
    gbar(flags, gen, ++epoch, blk, tid);

    // ---- S5: GRU2 ----
    gru_stage<512, 1536, 1024>(sm, p.gw2T, hA_next, p.ctx, hO_prev,
                               p.out_bi, p.out_bh, hO_next, ug, b0, tid);
    gbar(flags, gen, ++epoch, blk, tid);

    // ---- S6: mel/gate + prenet (32 b-blocks) ----
    if (blk < 32) {
      const int b = blk;
      sm.u.s6.xh[tid] = (tid < 512) ? lda(&hO_next[(b << 9) + tid])
                                    : lda(&p.ctx[(b << 9) + tid - 512]);
      __syncthreads();
      bool masked = step > p.mel_lens[b];
      {
        int m = tid & 127, ks = tid >> 7;
        const HU4* dp = (const HU4*)(p.decT + (size_t)m * 1024 + ks * 128);
        float a = 0.f;
#pragma unroll 4
        for (int it = 0; it < 16; it++) {
          HU4 raw = dp[it];
          int kb = ks * 128 + it * 8;
#pragma unroll
          for (int h2 = 0; h2 < 4; h2++) {
            float2 w = __half22float2(raw.h[h2]);
            a = fmaf(sm.u.s6.xh[kb + h2 * 2], w.x, a);
            a = fmaf(sm.u.s6.xh[kb + h2 * 2 + 1], w.y, a);
          }
        }
        sm.u.s6.red[tid] = a;
      }
      __syncthreads();
      if (tid < 128) {
        float mv = p.dec_b[tid];
#pragma unroll
        for (int j = 0; j < 8; j++) mv += sm.u.s6.red[tid + j * 128];
        sm.u.s6.mel[tid] = mv;
        p.out_mel[(size_t)b * 51200 + (size_t)step * 128 + tid] = masked ? 0.f : mv;
      }
      __syncthreads();
      sm.u.s6.red[tid] = sm.u.s6.xh[tid] * __half2float(p.gateh[tid]);
      __syncthreads();
      if (tid < 64) {
        float g = 0.f;
#pragma unroll
        for (int j = 0; j < 16; j++) g += sm.u.s6.red[tid + j * 64];
#pragma unroll
        for (int off = 32; off > 0; off >>= 1) g += __shfl_xor(g, off, 64);
        if (tid == 0) p.out_gate[b * 400 + step] = masked ? 1000.f : (g + p.gate_b[0]);
      }
      __syncthreads();
      {
        int pc = tid & 255, ks = tid >> 8;
        const HU4* wp = (const HU4*)(p.pre1T + (size_t)pc * 128 + ks * 32);
        float a = 0.f;
#pragma unroll
        for (int it = 0; it < 4; it++) {
          HU4 raw = wp[it];
          int kb = ks * 32 + it * 8;
#pragma unroll
          for (int h2 = 0; h2 < 4; h2++) {
            float2 w = __half22float2(raw.h[h2]);
            a = fmaf(sm.u.s6.mel[kb + h2 * 2], w.x, a);
            a = fmaf(sm.u.s6.mel[kb + h2 * 2 + 1], w.y, a);
          }
        }
        sm.u.s6.red[tid] = a;
      }
      __syncthreads();
      if (tid < 256) {
        float a = sm.u.s6.red[tid] + sm.u.s6.red[tid + 256] + sm.u.s6.red[tid + 512] + sm.u.s6.red[tid + 768];
        sm.u.s6.p1[tid] = fmaxf(a, 0.f);
      }
      __syncthreads();
      {
        int pc = tid & 255, ks = tid >> 8;
        const HU4* wp = (const HU4*)(p.pre2T + (size_t)pc * 256 + ks * 64);
        float a = 0.f;
#pragma unroll
        for (int it = 0; it < 8; it++) {
          HU4 raw = wp[it];
          int kb = ks * 64 + it * 8;
#pragma unroll
          for (int h2 = 0; h2 < 4; h2++) {
            float2 w = __half22float2(raw.h[h2]);
            a = fmaf(sm.u.s6.p1[kb + h2 * 2], w.x, a);
            a = fmaf(sm.u.s6.p1[kb + h2 * 2 + 1], w.y, a);
          }
        }
        sm.u.s6.red[tid] = a;
      }
      __syncthreads();
      if (tid < 256) {
        float a = sm.u.s6.red[tid] + sm.u.s6.red[tid + 256] + sm.u.s6.red[tid + 512] + sm.u.s6.red[tid + 768];
        sta(&p.decin[(b << 8) + tid], fmaxf(a, 0.f));
      }
    }
    gbar(flags, gen, ++epoch, blk, tid);
  }
}

extern "C" void kernel_launch(void* const* d_in, const int* in_sizes, int n_in,
                              void* d_out, int out_size, void* d_ws, size_t ws_size,
                              hipStream_t stream) {
  Params p;
  p.enc       = (const float*)d_in[0];
  p.text_lens = (const int*)d_in[2];
  p.mel_lens  = (const int*)d_in[3];
  p.pre_w1    = (const float*)d_in[5];
  p.pre_w2    = (const float*)d_in[6];
  p.attn_wi   = (const float*)d_in[7];
  p.attn_wh   = (const float*)d_in[8];
  p.attn_bi   = (const float*)d_in[9];
  p.attn_bh   = (const float*)d_in[10];
  p.q_w       = (const float*)d_in[11];
  p.k_w       = (const float*)d_in[12];
  p.score_w   = (const float*)d_in[13];
  p.score_b   = (const float*)d_in[14];
  p.conv_w    = (const float*)d_in[15];
  p.loc_w     = (const float*)d_in[16];
  p.loc_b     = (const float*)d_in[17];
  p.out_wi    = (const float*)d_in[18];
  p.out_wh    = (const float*)d_in[19];
  p.out_bi    = (const float*)d_in[20];
  p.out_bh    = (const float*)d_in[21];
  p.dec_w     = (const float*)d_in[22];
  p.dec_b     = (const float*)d_in[23];
  p.gate_w    = (const float*)d_in[24];
  p.gate_b    = (const float*)d_in[25];

  float* ws = (float*)d_ws;
  p.hkeys  = (__half*)(ws);                    // 8,388,608 halfs
  p.gw1T   = (__half*)(ws + 4194304);          // 2,621,440 halfs
  p.gw2T   = (__half*)(ws + 5505024);          // 3,145,728 halfs
  p.decT   = (__half*)(ws + 7077888);          // 131,072 halfs
  p.pre1T  = (__half*)(ws + 7143424);          // 32,768
  p.pre2T  = (__half*)(ws + 7159808);          // 65,536
  p.gateh  = (__half*)(ws + 7192576);          // 1,024
  p.locwh  = (__half*)(ws + 7193088);          // 16,384
  p.qwT    = (__half*)(ws + 7201280);          // 262,144 halfs
  p.hA     = ws + 7332352;                     // 2 x 16384
  p.hO     = ws + 7365120;                     // 2 x 16384
  p.attw   = ws + 7397888;                     // 16384
  p.attcum = ws + 7414272;                     // 16384
  p.ctx    = ws + 7430656;                     // 16384
  p.decin  = ws + 7447040;                     // 8192
  p.stateZ = p.hA;                             // contiguous zero region 122,880 floats
  p.ebuf   = ws + 7455232;                     // 16384
  p.zpart  = ws + 7471616;                     // 256
  p.ctxp   = ws + 7471872;                     // 131,072
  p.barc   = (unsigned*)(ws + 7602944);        // 512 uints (flags @0, gen @384)
  float* out = (float*)d_out;
  p.out_mel  = out;
  p.out_gate = out + 1638400;
  p.out_attn = out + 1651200;
  p.out_mask = out + 8204800;

  k_repack<<<2048, 256, 0, stream>>>(p);
  k_keys<<<dim3(128, 8), 512, 0, stream>>>(p);
  void* args[] = { (void*)&p };
  hipLaunchCooperativeKernel((const void*)mega, dim3(NBLK), dim3(NTHR), args, 0, stream);
}

// Round 7
// 41968.356 us; speedup vs baseline: 3.4450x; 1.3075x over previous
//
#include <hip/hip_runtime.h>
#include <hip/hip_fp16.h>
#include <math.h>

#define NBLK 256
#define NTHR 1024

__device__ __forceinline__ float fast_rcp(float x) {
#if __has_builtin(__builtin_amdgcn_rcpf)
  return __builtin_amdgcn_rcpf(x);
#else
  return 1.f / x;
#endif
}
__device__ __forceinline__ float fast_sigmoid(float x) { return fast_rcp(1.f + __expf(-x)); }
__device__ __forceinline__ float fast_tanh(float x) { return 1.f - 2.f * fast_rcp(1.f + __expf(2.f * x)); }

union HU2 { unsigned int u; __half2 h; };
union HU4 { uint4 u; __half2 h[4]; };
__device__ __forceinline__ float2 cvt2(unsigned int u) { HU2 t; t.u = u; return __half22float2(t.h); }

__device__ __forceinline__ void sta(float* p, float v) {
  __hip_atomic_store(p, v, __ATOMIC_RELAXED, __HIP_MEMORY_SCOPE_AGENT);
}
__device__ __forceinline__ float lda(const float* p) {
  return __hip_atomic_load(p, __ATOMIC_RELAXED, __HIP_MEMORY_SCOPE_AGENT);
}

struct Params {
  const float *enc, *pre_w1, *pre_w2, *attn_bi, *attn_bh;
  const float *q_w, *k_w, *score_w, *score_b, *conv_w, *loc_w, *loc_b;
  const float *out_bi, *out_bh, *dec_b, *gate_b;
  const float *attn_wi, *attn_wh, *out_wi, *out_wh, *dec_w, *gate_w;
  const int *text_lens, *mel_lens;
  __half *hkeys, *gw1T, *gw2T, *decT, *pre1T, *pre2T, *gateh, *locwh, *qwT;
  float *hA, *hO, *attw, *attcum, *decin, *ebuf, *zpart, *ctxacc, *stateZ;
  int *done;
  unsigned *barc;
  float *out_mel, *out_gate, *out_attn, *out_mask;
};

// two-level flag barrier (no L2 writeback/invalidate)
__device__ __forceinline__ void gbar(unsigned* flags, unsigned* gen, unsigned e,
                                     int blk, int tid) {
  __syncthreads();
  if (tid == 0) {
    asm volatile("s_waitcnt vmcnt(0) lgkmcnt(0)" ::: "memory");
    __hip_atomic_store(&flags[blk], e, __ATOMIC_RELAXED, __HIP_MEMORY_SCOPE_AGENT);
  }
  if (blk == 0) {
    if (tid < 64) {
      while (true) {
        bool ok = true;
#pragma unroll
        for (int j = 0; j < 4; j++) {
          unsigned v = __hip_atomic_load(&flags[tid * 4 + j], __ATOMIC_RELAXED,
                                         __HIP_MEMORY_SCOPE_AGENT);
          ok &= (v >= e);
        }
        if (__all(ok)) break;
        __builtin_amdgcn_s_sleep(1);
      }
      if (tid == 0)
        __hip_atomic_store(gen, e, __ATOMIC_RELAXED, __HIP_MEMORY_SCOPE_AGENT);
    }
  } else {
    if (tid == 0) {
      while (__hip_atomic_load(gen, __ATOMIC_RELAXED, __HIP_MEMORY_SCOPE_AGENT) < e)
        __builtin_amdgcn_s_sleep(2);
    }
  }
  asm volatile("" ::: "memory");
  __syncthreads();
}

// ---------------- prep: keys GEMM (fp16 out) ----------------
__global__ __launch_bounds__(512) void k_keys(Params p) {
  __shared__ float sA[16][132];
  __shared__ float sB[16][68];
  int tid = threadIdx.x;
  int row0 = blockIdx.x * 128, col0 = blockIdx.y * 64;
  float acc[4][4] = {};
  int r = tid >> 2, kq = tid & 3;
  int tx = tid & 15, ty = tid >> 4;
  for (int k0 = 0; k0 < 1024; k0 += 16) {
    __syncthreads();
    float4 a4 = *(const float4*)(p.enc + (size_t)(row0 + r) * 1024 + k0 + kq * 4);
    sA[kq * 4 + 0][r] = a4.x; sA[kq * 4 + 1][r] = a4.y;
    sA[kq * 4 + 2][r] = a4.z; sA[kq * 4 + 3][r] = a4.w;
    if (tid < 256) {
      int kb = tid >> 4, nb = (tid & 15) * 4;
      float4 b4 = *(const float4*)(p.k_w + (size_t)(k0 + kb) * 512 + col0 + nb);
      sB[kb][nb + 0] = b4.x; sB[kb][nb + 1] = b4.y;
      sB[kb][nb + 2] = b4.z; sB[kb][nb + 3] = b4.w;
    }
    __syncthreads();
#pragma unroll
    for (int k = 0; k < 16; k++) {
      float ar[4], br[4];
#pragma unroll
      for (int i = 0; i < 4; i++) { ar[i] = sA[k][ty * 4 + i]; br[i] = sB[k][tx * 4 + i]; }
#pragma unroll
      for (int i = 0; i < 4; i++)
#pragma unroll
        for (int j = 0; j < 4; j++) acc[i][j] = fmaf(ar[i], br[j], acc[i][j]);
    }
  }
#pragma unroll
  for (int i = 0; i < 4; i++)
#pragma unroll
    for (int j = 0; j < 4; j++)
      p.hkeys[(size_t)(row0 + ty * 4 + i) * 512 + col0 + tx * 4 + j] = __float2half(acc[i][j]);
}

// ---------------- prep: repack weights + zero state/barriers ----------------
__global__ __launch_bounds__(256) void k_repack(Params p) {
  const int gsz = gridDim.x * 256;
  const int t0 = blockIdx.x * 256 + threadIdx.x;
  for (int i = t0; i < 1280 * 512; i += gsz) {
    int r = i >> 9, u = i & 511;
    const float* src = (r < 768) ? p.attn_wi + (size_t)r * 1536 : p.attn_wh + (size_t)(r - 768) * 1536;
    __half2* d = (__half2*)(p.gw1T + ((size_t)i << 2));
    d[0] = __halves2half2(__float2half(src[u]), __float2half(src[512 + u]));
    d[1] = __halves2half2(__float2half(src[1024 + u]), __float2half(0.f));
  }
  for (int i = t0; i < 1536 * 512; i += gsz) {
    int r = i >> 9, u = i & 511;
    const float* src = (r < 1024) ? p.out_wi + (size_t)r * 1536 : p.out_wh + (size_t)(r - 1024) * 1536;
    __half2* d = (__half2*)(p.gw2T + ((size_t)i << 2));
    d[0] = __halves2half2(__float2half(src[u]), __float2half(src[512 + u]));
    d[1] = __halves2half2(__float2half(src[1024 + u]), __float2half(0.f));
  }
  for (int i = t0; i < 512 * 512; i += gsz) {
    int k = i >> 9, a = i & 511;
    p.qwT[(size_t)a * 512 + k] = __float2half(p.q_w[(size_t)k * 512 + a]);
  }
  for (int i = t0; i < 1024 * 128; i += gsz) {
    int k = i >> 7, m = i & 127;
    p.decT[(size_t)m * 1024 + k] = __float2half(p.dec_w[(size_t)k * 128 + m]);
  }
  for (int i = t0; i < 1024; i += gsz) p.gateh[i] = __float2half(p.gate_w[i]);
  for (int i = t0; i < 16384; i += gsz) p.locwh[i] = __float2half(p.loc_w[i]);
  for (int i = t0; i < 128 * 256; i += gsz) {
    int m = i >> 8, pc = i & 255;
    p.pre1T[(size_t)pc * 128 + m] = __float2half(p.pre_w1[(size_t)m * 256 + pc]);
  }
  for (int i = t0; i < 256 * 256; i += gsz) {
    int k = i >> 8, pc = i & 255;
    p.pre2T[(size_t)pc * 256 + k] = __float2half(p.pre_w2[(size_t)k * 256 + pc]);
  }
  for (int i = t0; i < 106496; i += gsz) p.stateZ[i] = 0.f;
  for (int i = t0; i < 16384; i += gsz) p.ctxacc[i] = 0.f;
  for (int i = t0; i < 512; i += gsz) p.barc[i] = 0u;
  for (int i = t0; i < 32; i += gsz) p.done[i] = 0;
  for (int i = t0; i < 12800; i += gsz) {
    int b = i / 400, t = i - b * 400;
    p.out_mask[i] = (t > p.mel_lens[b]) ? 1.f : 0.f;
  }
}

struct SMemMega {
  __half keysL[64 * 512];   // persistent P2 keys tile (64 KB)
  float ctxL[4][512];       // persistent ctx carry P3 -> next P1 (8 KB)
  float invZ[4];
  union {
    struct { float x[4][1536]; float4 part4[16][64]; } gr;
    struct { float locS[64][33]; float aw[94]; float ac[94]; float hA_s[512]; float qS[512];
             float qpart[2][512]; float cpred[8][512]; float eS[64]; } s3;
    struct { float xh[1024]; float red[1024]; float mel[128]; float p1[256]; } s6;
  } u;
};

// GRU compute: x staged in sm.u.gr.x; block owns 16 u's (uG = ug*16+u), 4 batches
template <int DXI, int RPK>
__device__ __forceinline__ void gru_compute(SMemMega& sm, const uint2* w512,
    const float* __restrict__ bi, const float* __restrict__ bh,
    float* __restrict__ hnext, int ug, int b0, int tid) {
  const int u = tid & 15, b2 = (tid >> 4) & 3, ks = tid >> 6;
  const int uG = (ug << 4) + u;
  float ar = 0.f, az = 0.f, ani = 0.f, anh = 0.f;
  const uint2* w = w512 + (size_t)(ks * RPK) * 512 + uG;
#pragma unroll 8
  for (int j = 0; j < RPK; j++) {
    uint2 wv = w[(size_t)j * 512];
    int r = ks * RPK + j;
    float x = sm.u.gr.x[b2][r];
    float2 f0 = cvt2(wv.x);
    float2 f1 = cvt2(wv.y);
    ar = fmaf(x, f0.x, ar);
    az = fmaf(x, f0.y, az);
    float t = x * f1.x;
    if (r < DXI) ani += t; else anh += t;
  }
  sm.u.gr.part4[ks][(u << 2) + b2] = make_float4(ar, az, ani, anh);
  __syncthreads();
  if (tid < 64) {
    int uu = tid >> 2, bb2 = tid & 3;
    float4 s = make_float4(0.f, 0.f, 0.f, 0.f);
#pragma unroll
    for (int l = 0; l < 16; l++) {
      float4 v = sm.u.gr.part4[l][(uu << 2) + bb2];
      s.x += v.x; s.y += v.y; s.z += v.z; s.w += v.w;
    }
    int uGf = (ug << 4) + uu;
    float r = fast_sigmoid(s.x + bi[uGf] + bh[uGf]);
    float z = fast_sigmoid(s.y + bi[512 + uGf] + bh[512 + uGf]);
    float n = fast_tanh(s.z + bi[1024 + uGf] + r * (s.w + bh[1024 + uGf]));
    float hv = sm.u.gr.x[bb2][DXI + uGf];
    sta(&hnext[((size_t)(b0 + bb2) << 9) + uGf], (1.f - z) * n + z * hv);
  }
}

__global__ __launch_bounds__(NTHR) void mega(Params p) {
  __shared__ SMemMega sm;
  const int blk = blockIdx.x, tid = threadIdx.x;
  // P1/P3 identity: same-ug blocks share weight tile and land on same XCD (blk%8 = ug%8)
  const int ug = blk & 31, bg = blk >> 5, b0 = bg * 4;
  // P2 identity: same-b blocks on same XCD (blk%8 = bS%8)
  const int bS = blk & 31, t8 = blk >> 5, t0g = t8 << 6;
  unsigned epoch = 0;
  unsigned* flags = p.barc;
  unsigned* gen = p.barc + 384;

  // ---- one-time: load keys tile into LDS, zero ctxL ----
  {
    const uint4* src = (const uint4*)(p.hkeys + (((size_t)(bS << 9) + t0g) << 9));
    uint4* dst = (uint4*)sm.keysL;
    for (int i = tid; i < 4096; i += NTHR) dst[i] = src[i];
    for (int i = tid; i < 2048; i += NTHR) sm.ctxL[i >> 9][i & 511] = 0.f;
  }
  __syncthreads();

#pragma clang loop unroll(disable)
  for (int step = 0; step < 400; step++) {
    const int par = step & 1;
    float* hA_prev = p.hA + par * 16384;
    float* hA_next = p.hA + (par ^ 1) * 16384;
    float* hO_prev = p.hO + par * 16384;
    float* hO_next = p.hO + (par ^ 1) * 16384;

    // ======== P1: GRU1 (+ zero ctxacc for this step's P2) ========
    {
      if (ug == 0) {
        for (int i = tid; i < 2048; i += NTHR)
          sta(&p.ctxacc[(b0 << 9) + i], 0.f);
      }
      for (int i = tid; i < 1024; i += NTHR) {
        int b2 = i >> 8, r = i & 255;
        sm.u.gr.x[b2][r] = lda(&p.decin[((b0 + b2) << 8) + r]);
      }
      for (int i = tid; i < 2048; i += NTHR) {
        int b2 = i >> 9, a = i & 511;
        sm.u.gr.x[b2][256 + a] = sm.ctxL[b2][a];
      }
      for (int i = tid; i < 2048; i += NTHR) {
        int b2 = i >> 9, a = i & 511;
        sm.u.gr.x[b2][768 + a] = lda(&hA_prev[((b0 + b2) << 9) + a]);
      }
      __syncthreads();
      gru_compute<768, 80>(sm, (const uint2*)p.gw1T, p.attn_bi, p.attn_bh,
                           hA_next, ug, b0, tid);
    }
    gbar(flags, gen, ++epoch, blk, tid);

    // ======== P2: conv + q + score + e + ctx-partial atomics ========
    {
      const int tlen = p.text_lens[bS];
      for (int j = tid; j < 94; j += NTHR) {
        int pp = t0g - 15 + j;
        bool ok = (unsigned)pp < 512u;
        sm.u.s3.aw[j] = ok ? lda(&p.attw[(bS << 9) + pp]) : 0.f;
        sm.u.s3.ac[j] = ok ? lda(&p.attcum[(bS << 9) + pp]) : 0.f;
      }
      if (tid < 512) sm.u.s3.hA_s[tid] = lda(&hA_next[(bS << 9) + tid]);
      __syncthreads();
      for (int i = tid; i < 2048; i += NTHR) {
        int tt = i >> 5, f = i & 31;
        const float* w0 = p.conv_w + f * 62;
        float a = 0.f;
#pragma unroll
        for (int k = 0; k < 31; k++)
          a = fmaf(w0[k], sm.u.s3.aw[tt + k], fmaf(w0[31 + k], sm.u.s3.ac[tt + k], a));
        sm.u.s3.locS[tt][f] = a;
      }
      {
        int a = tid & 511, ks = tid >> 9;
        const HU4* qp = (const HU4*)(p.qwT + (size_t)a * 512 + ks * 256);
        float q0 = 0.f, q1 = 0.f;
#pragma unroll 4
        for (int it = 0; it < 32; it++) {
          HU4 raw = qp[it];
          int kb = ks * 256 + it * 8;
#pragma unroll
          for (int h2 = 0; h2 < 4; h2++) {
            float2 w = __half22float2(raw.h[h2]);
            q0 = fmaf(sm.u.s3.hA_s[kb + h2 * 2], w.x, q0);
            q1 = fmaf(sm.u.s3.hA_s[kb + h2 * 2 + 1], w.y, q1);
          }
        }
        sm.u.s3.qpart[ks][a] = q0 + q1;
      }
      __syncthreads();
      if (tid < 512)
        sm.u.s3.qS[tid] = sm.u.s3.qpart[0][tid] + sm.u.s3.qpart[1][tid] + p.loc_b[tid];
      __syncthreads();
      const int lane = tid & 63, wv = tid >> 6;
      float acc[4][8];
      float4 qA = *(const float4*)&sm.u.s3.qS[lane * 8];
      float4 qB = *(const float4*)&sm.u.s3.qS[lane * 8 + 4];
#pragma unroll
      for (int j = 0; j < 4; j++) {
        int tL = wv * 4 + j;
        HU4 raw; raw.u = *(const uint4*)&sm.keysL[tL * 512 + lane * 8];
        float2 k0 = __half22float2(raw.h[0]), k1 = __half22float2(raw.h[1]);
        float2 k2 = __half22float2(raw.h[2]), k3 = __half22float2(raw.h[3]);
        acc[j][0] = qA.x + k0.x; acc[j][1] = qA.y + k0.y;
        acc[j][2] = qA.z + k1.x; acc[j][3] = qA.w + k1.y;
        acc[j][4] = qB.x + k2.x; acc[j][5] = qB.y + k2.y;
        acc[j][6] = qB.z + k3.x; acc[j][7] = qB.w + k3.y;
      }
#pragma unroll 4
      for (int f = 0; f < 32; f++) {
        HU4 rw; rw.u = *(const uint4*)(p.locwh + (size_t)f * 512 + lane * 8);
        float2 w0 = __half22float2(rw.h[0]), w1 = __half22float2(rw.h[1]);
        float2 w2 = __half22float2(rw.h[2]), w3 = __half22float2(rw.h[3]);
#pragma unroll
        for (int j = 0; j < 4; j++) {
          float lf = sm.u.s3.locS[wv * 4 + j][f];
          acc[j][0] = fmaf(lf, w0.x, acc[j][0]); acc[j][1] = fmaf(lf, w0.y, acc[j][1]);
          acc[j][2] = fmaf(lf, w1.x, acc[j][2]); acc[j][3] = fmaf(lf, w1.y, acc[j][3]);
          acc[j][4] = fmaf(lf, w2.x, acc[j][4]); acc[j][5] = fmaf(lf, w2.y, acc[j][5]);
          acc[j][6] = fmaf(lf, w3.x, acc[j][6]); acc[j][7] = fmaf(lf, w3.y, acc[j][7]);
        }
      }
      float4 sA = *(const float4*)(p.score_w + lane * 8);
      float4 sB = *(const float4*)(p.score_w + lane * 8 + 4);
      float sbias = p.score_b[0];
      float e_reg[4];
#pragma unroll
      for (int j = 0; j < 4; j++) {
        float pv = fast_tanh(acc[j][0]) * sA.x + fast_tanh(acc[j][1]) * sA.y +
                   fast_tanh(acc[j][2]) * sA.z + fast_tanh(acc[j][3]) * sA.w +
                   fast_tanh(acc[j][4]) * sB.x + fast_tanh(acc[j][5]) * sB.y +
                   fast_tanh(acc[j][6]) * sB.z + fast_tanh(acc[j][7]) * sB.w;
#pragma unroll
        for (int off = 32; off > 0; off >>= 1) pv += __shfl_xor(pv, off, 64);
        int t = t0g + wv * 4 + j;
        e_reg[j] = (t > tlen) ? 0.f : __expf(pv + sbias);
      }
      if (lane == 0) {
#pragma unroll
        for (int j = 0; j < 4; j++) sm.u.s3.eS[wv * 4 + j] = e_reg[j];
      }
      float cp[8] = {0.f, 0.f, 0.f, 0.f, 0.f, 0.f, 0.f, 0.f};
#pragma unroll
      for (int j = 0; j < 4; j++) {
        int tL = wv * 4 + j;
        HU4 raw; raw.u = *(const uint4*)&sm.keysL[tL * 512 + lane * 8];
        float2 k0 = __half22float2(raw.h[0]), k1 = __half22float2(raw.h[1]);
        float2 k2 = __half22float2(raw.h[2]), k3 = __half22float2(raw.h[3]);
        float e = e_reg[j];
        cp[0] = fmaf(e, k0.x, cp[0]); cp[1] = fmaf(e, k0.y, cp[1]);
        cp[2] = fmaf(e, k1.x, cp[2]); cp[3] = fmaf(e, k1.y, cp[3]);
        cp[4] = fmaf(e, k2.x, cp[4]); cp[5] = fmaf(e, k2.y, cp[5]);
        cp[6] = fmaf(e, k3.x, cp[6]); cp[7] = fmaf(e, k3.y, cp[7]);
      }
      __syncthreads();
      if (wv < 8) {
        float4* r0 = (float4*)&sm.u.s3.cpred[wv][lane * 8];
        r0[0] = make_float4(cp[0], cp[1], cp[2], cp[3]);
        r0[1] = make_float4(cp[4], cp[5], cp[6], cp[7]);
      }
      __syncthreads();
      if (wv >= 8) {
        float* r0 = &sm.u.s3.cpred[wv - 8][lane * 8];
#pragma unroll
        for (int i = 0; i < 8; i++) r0[i] += cp[i];
      }
      __syncthreads();
      if (tid < 512) {
        float s = 0.f;
#pragma unroll
        for (int j = 0; j < 8; j++) s += sm.u.s3.cpred[j][tid];
        atomicAdd(&p.ctxacc[(bS << 9) + tid], s);
      }
      if (tid < 64) {
        float e = sm.u.s3.eS[tid];
        sta(&p.ebuf[(bS << 9) + t0g + tid], e);
        float z = e;
#pragma unroll
        for (int off = 32; off > 0; off >>= 1) z += __shfl_xor(z, off, 64);
        if (tid == 0) sta(&p.zpart[bS * 8 + t8], z);
      }
    }
    gbar(flags, gen, ++epoch, blk, tid);

    // ======== P3: ctx normalize + GRU2 + fused S6 (heads+prenet) ========
    {
      if (tid < 4) {
        float Z = 0.f;
#pragma unroll
        for (int j = 0; j < 8; j++) Z += lda(&p.zpart[(b0 + tid) * 8 + j]);
        sm.invZ[tid] = fast_rcp(Z);
      }
      __syncthreads();
      for (int i = tid; i < 2048; i += NTHR) {
        int b2 = i >> 9, a = i & 511;
        sm.ctxL[b2][a] = lda(&p.ctxacc[((b0 + b2) << 9) + a]) * sm.invZ[b2];
      }
      if (ug == 0) {
        for (int i = tid; i < 2048; i += NTHR) {
          int b2 = i >> 9, t = i & 511;
          int bb = b0 + b2;
          float v = lda(&p.ebuf[(bb << 9) + t]) * sm.invZ[b2];
          sta(&p.attw[(bb << 9) + t], v);
          float oc = lda(&p.attcum[(bb << 9) + t]);
          sta(&p.attcum[(bb << 9) + t], oc + v);
          p.out_attn[(size_t)bb * 204800 + (size_t)step * 512 + t] = v;
        }
      }
      __syncthreads();
      // GRU2 staging: [hA_next | ctx | hO_prev]
      for (int i = tid; i < 2048; i += NTHR) {
        int b2 = i >> 9, a = i & 511;
        sm.u.gr.x[b2][a] = lda(&hA_next[((b0 + b2) << 9) + a]);
      }
      for (int i = tid; i < 2048; i += NTHR) {
        int b2 = i >> 9, a = i & 511;
        sm.u.gr.x[b2][512 + a] = sm.ctxL[b2][a];
      }
      for (int i = tid; i < 2048; i += NTHR) {
        int b2 = i >> 9, a = i & 511;
        sm.u.gr.x[b2][1024 + a] = lda(&hO_prev[((b0 + b2) << 9) + a]);
      }
      __syncthreads();
      gru_compute<1024, 96>(sm, (const uint2*)p.gw2T, p.out_bi, p.out_bh,
                            hO_next, ug, b0, tid);
      asm volatile("s_waitcnt vmcnt(0)" ::: "memory");
      __syncthreads();
      if (tid < 4) atomicAdd(&p.done[b0 + tid], 1);
      // fused S6: blocks ug==0..3 each handle one batch of their bg
      if (ug < 4) {
        const int bb = b0 + ug;
        if (tid == 0) {
          int target = 32 * (step + 1);
          while (__hip_atomic_load(&p.done[bb], __ATOMIC_RELAXED,
                                   __HIP_MEMORY_SCOPE_AGENT) < target)
            __builtin_amdgcn_s_sleep(2);
        }
        __syncthreads();
        sm.u.s6.xh[tid] = (tid < 512) ? lda(&hO_next[(bb << 9) + tid])
                                      : sm.ctxL[ug][tid - 512];
        __syncthreads();
        bool masked = step > p.mel_lens[bb];
        {
          int m = tid & 127, ks = tid >> 7;
          const HU4* dp = (const HU4*)(p.decT + (size_t)m * 1024 + ks * 128);
          float a = 0.f;
#pragma unroll 4
          for (int it = 0; it < 16; it++) {
            HU4 raw = dp[it];
            int kb = ks * 128 + it * 8;
#pragma unroll
            for (int h2 = 0; h2 < 4; h2++) {
              float2 w = __half22float2(raw.h[h2]);
              a = fmaf(sm.u.s6.xh[kb + h2 * 2], w.x, a);
              a = fmaf(sm.u.s6.xh[kb + h2 * 2 + 1], w.y, a);
            }
          }
          sm.u.s6.red[tid] = a;
        }
        __syncthreads();
        if (tid < 128) {
          float mv = p.dec_b[tid];
#pragma unroll
          for (int j = 0; j < 8; j++) mv += sm.u.s6.red[tid + j * 128];
          sm.u.s6.mel[tid] = mv;
          p.out_mel[(size_t)bb * 51200 + (size_t)step * 128 + tid] = masked ? 0.f : mv;
        }
        __syncthreads();
        sm.u.s6.red[tid] = sm.u.s6.xh[tid] * __half2float(p.gateh[tid]);
        __syncthreads();
        if (tid < 64) {
          float g = 0.f;
#pragma unroll
          for (int j = 0; j < 16; j++) g += sm.u.s6.red[tid + j * 64];
#pragma unroll
          for (int off = 32; off > 0; off >>= 1) g += __shfl_xor(g, off, 64);
          if (tid == 0) p.out_gate[bb * 400 + step] = masked ? 1000.f : (g + p.gate_b[0]);
        }
        __syncthreads();
        {
          int pc = tid & 255, ks = tid >> 8;
          const HU4* wp = (const HU4*)(p.pre1T + (size_t)pc * 128 + ks * 32);
          float a = 0.f;
#pragma unroll
          for (int it = 0; it < 4; it++) {
            HU4 raw = wp[it];
            int kb = ks * 32 + it * 8;
#pragma unroll
            for (int h2 = 0; h2 < 4; h2++) {
              float2 w = __half22float2(raw.h[h2]);
              a = fmaf(sm.u.s6.mel[kb + h2 * 2], w.x, a);
              a = fmaf(sm.u.s6.mel[kb + h2 * 2 + 1], w.y, a);
            }
          }
          sm.u.s6.red[tid] = a;
        }
        __syncthreads();
        if (tid < 256) {
          float a = sm.u.s6.red[tid] + sm.u.s6.red[tid + 256] +
                    sm.u.s6.red[tid + 512] + sm.u.s6.red[tid + 768];
          sm.u.s6.p1[tid] = fmaxf(a, 0.f);
        }
        __syncthreads();
        {
          int pc = tid & 255, ks = tid >> 8;
          const HU4* wp = (const HU4*)(p.pre2T + (size_t)pc * 256 + ks * 64);
          float a = 0.f;
#pragma unroll
          for (int it = 0; it < 8; it++) {
            HU4 raw = wp[it];
            int kb = ks * 64 + it * 8;
#pragma unroll
            for (int h2 = 0; h2 < 4; h2++) {
              float2 w = __half22float2(raw.h[h2]);
              a = fmaf(sm.u.s6.p1[kb + h2 * 2], w.x, a);
              a = fmaf(sm.u.s6.p1[kb + h2 * 2 + 1], w.y, a);
            }
          }
          sm.u.s6.red[tid] = a;
        }
        __syncthreads();
        if (tid < 256) {
          float a = sm.u.s6.red[tid] + sm.u.s6.red[tid + 256] +
                    sm.u.s6.red[tid + 512] + sm.u.s6.red[tid + 768];
          sta(&p.decin[(bb << 8) + tid], fmaxf(a, 0.f));
        }
      }
    }
    gbar(flags, gen, ++epoch, blk, tid);
  }
}

extern "C" void kernel_launch(void* const* d_in, const int* in_sizes, int n_in,
                              void* d_out, int out_size, void* d_ws, size_t ws_size,
                              hipStream_t stream) {
  Params p;
  p.enc       = (const float*)d_in[0];
  p.text_lens = (const int*)d_in[2];
  p.mel_lens  = (const int*)d_in[3];
  p.pre_w1    = (const float*)d_in[5];
  p.pre_w2    = (const float*)d_in[6];
  p.attn_wi   = (const float*)d_in[7];
  p.attn_wh   = (const float*)d_in[8];
  p.attn_bi   = (const float*)d_in[9];
  p.attn_bh   = (const float*)d_in[10];
  p.q_w       = (const float*)d_in[11];
  p.k_w       = (const float*)d_in[12];
  p.score_w   = (const float*)d_in[13];
  p.score_b   = (const float*)d_in[14];
  p.conv_w    = (const float*)d_in[15];
  p.loc_w     = (const float*)d_in[16];
  p.loc_b     = (const float*)d_in[17];
  p.out_wi    = (const float*)d_in[18];
  p.out_wh    = (const float*)d_in[19];
  p.out_bi    = (const float*)d_in[20];
  p.out_bh    = (const float*)d_in[21];
  p.dec_w     = (const float*)d_in[22];
  p.dec_b     = (const float*)d_in[23];
  p.gate_w    = (const float*)d_in[24];
  p.gate_b    = (const float*)d_in[25];

  float* ws = (float*)d_ws;
  p.hkeys  = (__half*)(ws);                    // 8,388,608 halfs
  p.gw1T   = (__half*)(ws + 4194304);
  p.gw2T   = (__half*)(ws + 5505024);
  p.decT   = (__half*)(ws + 7077888);
  p.pre1T  = (__half*)(ws + 7143424);
  p.pre2T  = (__half*)(ws + 7159808);
  p.gateh  = (__half*)(ws + 7192576);
  p.locwh  = (__half*)(ws + 7193088);
  p.qwT    = (__half*)(ws + 7201280);
  p.hA     = ws + 7332352;
  p.hO     = ws + 7365120;
  p.attw   = ws + 7397888;
  p.attcum = ws + 7414272;
  p.decin  = ws + 7430656;
  p.stateZ = p.hA;                             // zero region: hA,hO,attw,attcum,decin = 106,496
  p.ebuf   = ws + 7438848;
  p.zpart  = ws + 7455232;
  p.ctxacc = ws + 7455488;
  p.done   = (int*)(ws + 7471872);             // 32 ints
  p.barc   = (unsigned*)(ws + 7471904);        // 512 uints
  float* out = (float*)d_out;
  p.out_mel  = out;
  p.out_gate = out + 1638400;
  p.out_attn = out + 1651200;
  p.out_mask = out + 8204800;

  k_repack<<<2048, 256, 0, stream>>>(p);
  k_keys<<<dim3(128, 8), 512, 0, stream>>>(p);
  void* args[] = { (void*)&p };
  hipLaunchCooperativeKernel((const void*)mega, dim3(NBLK), dim3(NTHR), args, 0, stream);
}